// Round 4
// baseline (280.509 us; speedup 1.0000x reference)
//
#include <hip/hip_runtime.h>
#include <cmath>

constexpr int NN  = 50000;          // nodes
constexpr int EE  = 800000;         // raw edges
constexpr int E2C = EE + NN;        // edges incl. self loops = 850000
constexpr int DIM = 128;            // input dim to every layer's GEMM

// bucketed counting sort params
constexpr int NBUCK = 256;          // dst buckets
constexpr int BW    = 196;          // bucket width: 196*256 = 50176 >= NN
constexpr int EPT   = 8;            // edges per thread (bin)
constexpr int CH    = 256 * EPT;    // 2048 edges per block
constexpr int NB_B  = (E2C + CH - 1) / CH;  // 416 blocks
constexpr int CAP   = 4096;         // per-bucket pairs capacity (mean 3332, +13 sigma)
constexpr int SCAP  = 5120;         // per-bucket padded sorted capacity (mean ~3630)

using bf16x8 = __attribute__((ext_vector_type(8))) short;
using f32x4  = __attribute__((ext_vector_type(4))) float;
using u32x4  = __attribute__((ext_vector_type(4))) unsigned int;

// bf16 helpers (storage bf16, math fp32)
__device__ inline unsigned bf16rne(float f) {
    unsigned u = __builtin_bit_cast(unsigned, f);
    return (u + 0x7fffu + ((u >> 16) & 1u)) >> 16;     // round-nearest-even
}
__device__ inline float bflo(unsigned u) { return __builtin_bit_cast(float, u << 16); }
__device__ inline float bfhi(unsigned u) { return __builtin_bit_cast(float, u & 0xffff0000u); }

// ---------------------------------------------------------------------------
// W[k,c] fp32 -> Wt[c,k] bf16, all three weights in one kernel.
// Also zeroes bcursor (replaces a separate memset dispatch).
// ---------------------------------------------------------------------------
__global__ __launch_bounds__(256) void cvt_weights(
    const float* __restrict__ W1, const float* __restrict__ W2,
    const float* __restrict__ W3,
    unsigned short* __restrict__ W1t, unsigned short* __restrict__ W2t,
    unsigned short* __restrict__ W3t, int* __restrict__ bcursor)
{
    int g = blockIdx.x * 256 + threadIdx.x;
    if (g < NBUCK) bcursor[g] = 0;
    const float* W; unsigned short* Wt; int cols;
    if (g < 2048)      { W = W1; Wt = W1t; cols = 128; }
    else if (g < 4096) { W = W2; Wt = W2t; cols = 128; g -= 2048; }
    else if (g < 4608) { W = W3; Wt = W3t; cols = 32;  g -= 4096; }
    else return;
    int c  = g / 16;
    int k8 = (g % 16) * 8;
    unsigned up[4];
    #pragma unroll
    for (int j = 0; j < 4; ++j) {
        float a = W[(k8 + 2 * j) * cols + c];
        float b = W[(k8 + 2 * j + 1) * cols + c];
        up[j] = bf16rne(a) | (bf16rne(b) << 16);
    }
    uint4 u; u.x = up[0]; u.y = up[1]; u.z = up[2]; u.w = up[3];
    *(uint4*)(Wt + c * 128 + k8) = u;
}

// ---------------------------------------------------------------------------
// MFMA GEMM + fused attention coefficients.
// h/asrc/adst stores are NON-TEMPORAL: consumers (aggr on all 8 XCDs) would
// otherwise miss against lines dirty in remote, non-coherent L2s — the
// writeback-then-fetch path is the suspected 2.5 TB/s cap on aggr (r1/r2
// counters: FETCH_SIZE ~ 8 XCD x full h; streaming fills hit 6.1 TB/s).
// ---------------------------------------------------------------------------
template<int NT, int NH, bool F32IN>
__global__ __launch_bounds__(256) void gemm_mfma(
    const void* __restrict__ inv, const unsigned short* __restrict__ Wt,
    const float* __restrict__ a_s, const float* __restrict__ a_d,
    unsigned short* __restrict__ hout, float* __restrict__ asrc,
    float* __restrict__ adst)
{
    constexpr int COLS = NT * 16;
    constexpr int TPH  = NT / NH;        // tiles per head (2)
    const int lane = threadIdx.x & 63;
    const int wave = threadIdx.x >> 6;
    const int m    = lane & 15;
    const int quad = lane >> 4;
    const int n0   = blockIdx.x * 64 + wave * 16;

    int arow = n0 + m; if (arow >= NN) arow = NN - 1;

    f32x4 acc[NT] = {};
    #pragma unroll
    for (int kq = 0; kq < 4; ++kq) {
        bf16x8 a;
        if constexpr (F32IN) {
            const float* ap = (const float*)inv + (long long)arow * 128 + quad * 8 + kq * 32;
            float4 v0 = *(const float4*)ap;
            float4 v1 = *(const float4*)(ap + 4);
            a[0] = (short)bf16rne(v0.x); a[1] = (short)bf16rne(v0.y);
            a[2] = (short)bf16rne(v0.z); a[3] = (short)bf16rne(v0.w);
            a[4] = (short)bf16rne(v1.x); a[5] = (short)bf16rne(v1.y);
            a[6] = (short)bf16rne(v1.z); a[7] = (short)bf16rne(v1.w);
        } else {
            a = *(const bf16x8*)((const unsigned short*)inv
                    + (long long)arow * 128 + quad * 8 + kq * 32);
        }
        #pragma unroll
        for (int t = 0; t < NT; ++t) {
            bf16x8 b = *(const bf16x8*)(Wt + (t * 16 + m) * 128 + kq * 32 + quad * 8);
            acc[t] = __builtin_amdgcn_mfma_f32_16x16x32_bf16(a, b, acc[t], 0, 0, 0);
        }
    }

    // ---- h store (non-temporal: no L2 allocate, land clean in L3) ----
    #pragma unroll
    for (int r = 0; r < 4; ++r) {
        int node = n0 + quad * 4 + r;
        if (node < NN) {
            #pragma unroll
            for (int t = 0; t < NT; ++t)
                __builtin_nontemporal_store(
                    (unsigned short)bf16rne(acc[t][r]),
                    hout + (long long)node * COLS + t * 16 + m);
        }
    }

    // ---- fused alpha: per-head dots + 16-lane reduction ----
    float asv[NT], adv[NT];
    #pragma unroll
    for (int t = 0; t < NT; ++t) { asv[t] = a_s[t * 16 + m]; adv[t] = a_d[t * 16 + m]; }

    #pragma unroll
    for (int r = 0; r < 4; ++r) {
        const int node = n0 + quad * 4 + r;
        #pragma unroll
        for (int hh = 0; hh < NH; ++hh) {
            float ps = 0.f, pd = 0.f;
            #pragma unroll
            for (int q = 0; q < TPH; ++q) {
                int t = hh * TPH + q;
                ps = fmaf(acc[t][r], asv[t], ps);
                pd = fmaf(acc[t][r], adv[t], pd);
            }
            #pragma unroll
            for (int off = 8; off > 0; off >>= 1) {
                ps += __shfl_down(ps, off, 16);
                pd += __shfl_down(pd, off, 16);
            }
            if (m == 0 && node < NN) {
                __builtin_nontemporal_store(ps, asrc + node * NH + hh);
                __builtin_nontemporal_store(pd, adst + node * NH + hh);
            }
        }
    }

    // sentinel row: pads in sorted point to node NN -> exp(-1e30) == 0
    if (blockIdx.x == 0 && threadIdx.x == 0) {
        #pragma unroll
        for (int hh = 0; hh < NH; ++hh) asrc[NN * NH + hh] = -1e30f;
    }
}

// ---------------------------------------------------------------------------
// CSR build (2 kernels). pairs segmented per bucket (CAP each); sorted is
// segmented per bucket (SCAP each) with every node's range padded to a
// multiple of 4; pad slots hold sentinel node NN. Per-RANK range stored as
// int2 (beg, end); perm[rank] = node, ranks degree-sorted within bucket.
// Record packing: src:16 | dlocal:8 | bucket:8.
// ---------------------------------------------------------------------------
__global__ __launch_bounds__(256) void bucket_bin(
    const int* __restrict__ ei, int* __restrict__ bcursor,
    unsigned* __restrict__ pairs)
{
    __shared__ int cnt[NBUCK];
    __shared__ int scanex[NBUCK];
    __shared__ int base[NBUCK];
    __shared__ int cur[NBUCK];
    __shared__ unsigned stage[CH];       // 8 KB

    const int tid = threadIdx.x;
    const long long e0 = (long long)blockIdx.x * CH;
    cnt[tid] = 0;
    __syncthreads();

    unsigned rec[EPT]; int bk[EPT];
    #pragma unroll
    for (int j = 0; j < EPT; ++j) {
        long long e = e0 + tid + j * 256;
        bool valid = e < E2C;
        int ss = 0, dd = 0;
        if (valid) {
            if (e < EE) { ss = ei[e]; dd = ei[EE + e]; }
            else        { ss = dd = (int)(e - EE); }
        }
        int b = dd / BW;
        bk[j]  = valid ? b : -1;
        rec[j] = (unsigned)ss | ((unsigned)(dd - b * BW) << 16) | ((unsigned)b << 24);
        if (valid) atomicAdd(&cnt[b], 1);
    }
    __syncthreads();

    const int myc = cnt[tid];
    scanex[tid] = myc;
    __syncthreads();
    for (int off = 1; off < NBUCK; off <<= 1) {
        int t = (tid >= off) ? scanex[tid - off] : 0;
        __syncthreads();
        scanex[tid] += t;
        __syncthreads();
    }
    int excl = scanex[tid] - myc;
    __syncthreads();
    scanex[tid] = excl;
    cur[tid]    = excl;
    base[tid]   = atomicAdd(&bcursor[tid], myc);   // reserve chunk in segment
    __syncthreads();

    #pragma unroll
    for (int j = 0; j < EPT; ++j) {
        if (bk[j] >= 0) {
            int p = atomicAdd(&cur[bk[j]], 1);
            stage[p] = rec[j];
        }
    }
    __syncthreads();

    const int total = (e0 + CH <= E2C) ? CH : (int)(E2C - e0);
    for (int j = tid; j < total; j += 256) {
        unsigned p = stage[j];
        int b = (int)(p >> 24);
        pairs[(size_t)b * CAP + base[b] + (j - scanex[b])] = p;
    }
}

__global__ __launch_bounds__(256) void bucket_sort(
    const int* __restrict__ bcursor, const unsigned* __restrict__ pairs,
    int2* __restrict__ rowp, unsigned short* __restrict__ sorted_src,
    unsigned short* __restrict__ perm)
{
    __shared__ int deg[256];
    __shared__ int scn[256];
    __shared__ int cur[256];
    __shared__ int hist2[64];
    __shared__ int scn2[64];
    __shared__ int cur2[64];
    const int b  = blockIdx.x;
    const int n0 = b * BW;
    const int n1 = (n0 + BW < NN) ? n0 + BW : NN;
    const int nloc = n1 - n0;
    const int tid = threadIdx.x;
    const int mycnt = bcursor[b];
    const unsigned* seg = pairs + (size_t)b * CAP;
    const int base = b * SCAP;

    deg[tid] = 0;
    if (tid < 64) hist2[tid] = 0;
    __syncthreads();
    for (int i = tid; i < mycnt; i += 256)
        atomicAdd(&deg[(seg[i] >> 16) & 0xff], 1);
    __syncthreads();

    const int pv = (deg[tid] + 3) & ~3;            // degree padded to mult of 4
    int it = pv >> 2; if (it > 63) it = 63;        // iteration-count key
    scn[tid] = pv;
    if (tid < nloc) atomicAdd(&hist2[it], 1);
    __syncthreads();
    for (int off = 1; off < 256; off <<= 1) {
        int t = (tid >= off) ? scn[tid - off] : 0;
        __syncthreads();
        scn[tid] += t;
        __syncthreads();
    }
    // scan the 64 iteration-count bins (degree-rank within bucket)
    if (tid < 64) scn2[tid] = hist2[tid];
    __syncthreads();
    for (int off = 1; off < 64; off <<= 1) {
        int t = (tid >= off && tid < 64) ? scn2[tid - off] : 0;
        __syncthreads();
        if (tid < 64) scn2[tid] += t;
        __syncthreads();
    }
    if (tid < 64) cur2[tid] = scn2[tid] - hist2[tid];
    __syncthreads();

    const int totalp = scn[255];
    const int pexcl  = scn[tid] - pv;
    cur[tid] = base + pexcl;
    if (tid < nloc) {
        int rank = atomicAdd(&cur2[it], 1);        // degree-sorted local rank
        perm[n0 + rank] = (unsigned short)(n0 + tid);
        rowp[n0 + rank] = make_int2(base + pexcl, base + pexcl + pv);
    }
    __syncthreads();

    // sentinel-fill padded extent (+8 prefetch slack, capped at own segment),
    // then scatter real entries over it
    int lim = totalp + 8; if (lim > SCAP) lim = SCAP;
    for (int i = tid; i < lim; i += 256)
        sorted_src[base + i] = (unsigned short)NN;
    if (b == NBUCK - 1 && tid < 8)
        sorted_src[NBUCK * SCAP + tid] = (unsigned short)NN;   // global slack
    __syncthreads();
    for (int i = tid; i < mycnt; i += 256) {
        unsigned p = seg[i];
        int pos = atomicAdd(&cur[(p >> 16) & 0xff], 1);
        sorted_src[pos] = (unsigned short)(p & 0xffff);
    }
}

// ---------------------------------------------------------------------------
// CSR gather aggregation over bf16 h: padded mask-free 4-deep batches,
// software-pipelined one batch ahead (idx two batches ahead). 8 ch/lane
// (COLS/8 lanes/node) for max thread-level parallelism. Output stores are
// non-temporal (consumed next by gemm across all XCDs).
// ---------------------------------------------------------------------------
template<int COLS, int NH, bool DO_ELU, bool OUTBF>
__global__ __launch_bounds__(256) void aggr_csr(
    const unsigned short* __restrict__ perm,
    const int2* __restrict__ rowp, const unsigned short* __restrict__ sorted_src,
    const unsigned short* __restrict__ hin,
    const float* __restrict__ asrc, const float* __restrict__ adst,
    const float* __restrict__ bias, void* __restrict__ outv)
{
    constexpr int TPN = COLS / 8;             // lanes per node: 16 or 4
    constexpr int USTR = COLS / 2;            // uints per h row
    int t = blockIdx.x * 256 + threadIdx.x;
    int rk = t / TPN;                         // degree-sorted rank
    int lc = t % TPN;                         // owns channels 8*lc .. 8*lc+7
    if (rk >= NN) return;
    const int d = perm[rk];                   // actual node
    const int cc = lc * 8;
    const int head = cc / 32;                 // 0..NH-1 (uniform per lane group)
    const float ad = adst[d * NH + head];
    const int2 be = rowp[rk];
    const int beg = be.x, end = be.y;         // 4-aligned; deg >= 1 => beg < end
    const uint* hp = (const uint*)hin + cc / 2;

    float num[8] = {};
    float den = 0.f;

    // ---- pipeline prologue: batch 0 fully issued, idx for batch 1 issued ----
    ushort4 v0 = *(const ushort4*)&sorted_src[beg];
    int s0[4] = {v0.x, v0.y, v0.z, v0.w};
    float a0[4]; uint4 H0[4];
    #pragma unroll
    for (int j = 0; j < 4; ++j) a0[j] = asrc[s0[j] * NH + head];
    #pragma unroll
    for (int j = 0; j < 4; ++j) H0[j] = *(const uint4*)&hp[(long long)s0[j] * USTR];
    ushort4 sv = *(const ushort4*)&sorted_src[beg + 4];

    for (int i = beg; i < end; i += 4) {
        // idx for batch i+8 (segment slack sentinel-filled)
        ushort4 nxt = *(const ushort4*)&sorted_src[i + 8];
        // issue loads for batch i+4 (sentinel pads -> node NN, L1-hot)
        int s1[4] = {sv.x, sv.y, sv.z, sv.w};
        float a1[4]; uint4 H1[4];
        #pragma unroll
        for (int j = 0; j < 4; ++j) a1[j] = asrc[s1[j] * NH + head];
        #pragma unroll
        for (int j = 0; j < 4; ++j) H1[j] = *(const uint4*)&hp[(long long)s1[j] * USTR];
        // compute batch i
        #pragma unroll
        for (int j = 0; j < 4; ++j) {
            float l = a0[j] + ad; l = l > 0.f ? l : 0.2f * l;
            float w = __builtin_expf(l);
            den += w;
            num[0] = fmaf(w, bflo(H0[j].x), num[0]); num[1] = fmaf(w, bfhi(H0[j].x), num[1]);
            num[2] = fmaf(w, bflo(H0[j].y), num[2]); num[3] = fmaf(w, bfhi(H0[j].y), num[3]);
            num[4] = fmaf(w, bflo(H0[j].z), num[4]); num[5] = fmaf(w, bfhi(H0[j].z), num[5]);
            num[6] = fmaf(w, bflo(H0[j].w), num[6]); num[7] = fmaf(w, bfhi(H0[j].w), num[7]);
        }
        // rotate
        #pragma unroll
        for (int j = 0; j < 4; ++j) { s0[j] = s1[j]; a0[j] = a1[j]; H0[j] = H1[j]; }
        sv = nxt;
    }

    float inv = 1.f / (den + 1e-16f);
    float v[8];
    #pragma unroll
    for (int j = 0; j < 8; ++j) {
        v[j] = num[j] * inv + bias[cc + j];
        if (DO_ELU) v[j] = v[j] > 0.f ? v[j] : expm1f(v[j]);
    }
    if constexpr (OUTBF) {
        u32x4 u;
        u[0] = bf16rne(v[0]) | (bf16rne(v[1]) << 16);
        u[1] = bf16rne(v[2]) | (bf16rne(v[3]) << 16);
        u[2] = bf16rne(v[4]) | (bf16rne(v[5]) << 16);
        u[3] = bf16rne(v[6]) | (bf16rne(v[7]) << 16);
        __builtin_nontemporal_store(
            u, (u32x4*)((unsigned short*)outv + (long long)d * COLS + cc));
    } else {
        float4 o0 = {v[0], v[1], v[2], v[3]};
        float4 o1 = {v[4], v[5], v[6], v[7]};
        float* out = (float*)outv;
        *(float4*)&out[(long long)d * COLS + cc]     = o0;
        *(float4*)&out[(long long)d * COLS + cc + 4] = o1;
    }
}

// ---------------------------------------------------------------------------
extern "C" void kernel_launch(void* const* d_in, const int* in_sizes, int n_in,
                              void* d_out, int out_size, void* d_ws, size_t ws_size,
                              hipStream_t stream)
{
    const float* x   = (const float*)d_in[0];
    const int*   ei  = (const int*)  d_in[1];
    const float* W1  = (const float*)d_in[2];
    const float* as1 = (const float*)d_in[3];
    const float* ad1 = (const float*)d_in[4];
    const float* b1  = (const float*)d_in[5];
    const float* W2  = (const float*)d_in[6];
    const float* as2 = (const float*)d_in[7];
    const float* ad2 = (const float*)d_in[8];
    const float* b2  = (const float*)d_in[9];
    const float* W3  = (const float*)d_in[10];
    const float* as3 = (const float*)d_in[11];
    const float* ad3 = (const float*)d_in[12];
    const float* b3  = (const float*)d_in[13];
    float* out = (float*)d_out;

    // workspace layout (16B-aligned bf16 buffers first). H16 has sentinel row.
    unsigned short* H16 = (unsigned short*)d_ws;          // (N+1)*128 bf16
    unsigned short* O16 = H16 + (size_t)(NN + 1) * 128;   // N*128 bf16
    unsigned short* P16 = O16 + (size_t)NN * 128;         // N*128 bf16
    unsigned short* W1t = P16 + (size_t)NN * 128;         // 128*128 bf16
    unsigned short* W2t = W1t + 128 * 128;
    unsigned short* W3t = W2t + 128 * 128;                // 32*128
    float* ASRC = (float*)(W3t + 32 * 128);               // (N+1)*4
    float* ADST = ASRC + (size_t)(NN + 1) * 4;            // N*4
    int2* rowp  = (int2*)(ADST + (size_t)NN * 4);         // NN int2 (rank-indexed)
    unsigned short* sorted = (unsigned short*)(rowp + NN);         // NBUCK*SCAP+8 u16
    int* bcursor = (int*)(sorted + (size_t)NBUCK * SCAP + 8);      // NBUCK
    unsigned short* perm = (unsigned short*)(bcursor + NBUCK);     // NN u16 (rank->node)
    size_t off = ((size_t)(perm + NN) - (size_t)d_ws + 15) & ~(size_t)15;
    unsigned* pairs = (unsigned*)((char*)d_ws + off);     // NBUCK*CAP u32 (4 MB)

    const int gCvtW    = (4608 + 255) / 256;             // 18
    const int gGemm    = (NN + 63) / 64;                 // 782
    const int gAggr128 = (NN * 16 + 255) / 256;          // 3125
    const int gAggr32  = (NN * 4 + 255) / 256;           // 782

    // ---- weight conversion (+ bcursor zeroing), then CSR build ----
    cvt_weights<<<gCvtW, 256, 0, stream>>>(W1, W2, W3, W1t, W2t, W3t, bcursor);
    bucket_bin<<<NB_B, 256, 0, stream>>>(ei, bcursor, pairs);
    bucket_sort<<<NBUCK, 256, 0, stream>>>(bcursor, pairs, rowp, sorted, perm);

    // ---- layer 1 (128 -> 4x32 concat, ELU); fp32 x read directly ----
    gemm_mfma<8, 4, true><<<gGemm, 256, 0, stream>>>(x, W1t, as1, ad1, H16, ASRC, ADST);
    aggr_csr<128, 4, true, true><<<gAggr128, 256, 0, stream>>>(
        perm, rowp, sorted, H16, ASRC, ADST, b1, O16);

    // ---- layer 2 (128 -> 4x32 concat, ELU) ----
    gemm_mfma<8, 4, false><<<gGemm, 256, 0, stream>>>(O16, W2t, as2, ad2, H16, ASRC, ADST);
    aggr_csr<128, 4, true, true><<<gAggr128, 256, 0, stream>>>(
        perm, rowp, sorted, H16, ASRC, ADST, b2, P16);

    // ---- layer 3 (128 -> 32, 1 head, no concat) ----
    gemm_mfma<2, 1, false><<<gGemm, 256, 0, stream>>>(P16, W3t, as3, ad3, H16, ASRC, ADST);
    aggr_csr<32, 1, false, false><<<gAggr32, 256, 0, stream>>>(
        perm, rowp, sorted, H16, ASRC, ADST, b3, out);
}

// Round 5
// 271.552 us; speedup vs baseline: 1.0330x; 1.0330x over previous
//
#include <hip/hip_runtime.h>
#include <cmath>

constexpr int NN  = 50000;          // nodes
constexpr int EE  = 800000;         // raw edges
constexpr int E2C = EE + NN;        // edges incl. self loops = 850000

// bucketed counting sort params
constexpr int NBUCK = 256;          // dst buckets
constexpr int BW    = 196;          // bucket width: 196*256 = 50176 >= NN
constexpr int EPT   = 8;            // edges per thread (bin)
constexpr int CH    = 256 * EPT;    // 2048 edges per block
constexpr int NB_B  = (E2C + CH - 1) / CH;  // 416 blocks
constexpr int CAP   = 4096;         // per-bucket pairs capacity (mean 3332, +13 sigma)
constexpr int SCAP  = 5120;         // per-bucket padded sorted capacity (mean ~3630)

using bf16x8 = __attribute__((ext_vector_type(8))) short;
using f32x4  = __attribute__((ext_vector_type(4))) float;

// bf16 helpers (storage bf16, math fp32)
__device__ inline unsigned bf16rne(float f) {
    unsigned u = __builtin_bit_cast(unsigned, f);
    return (u + 0x7fffu + ((u >> 16) & 1u)) >> 16;     // round-nearest-even
}
__device__ inline float bflo(unsigned u) { return __builtin_bit_cast(float, u << 16); }
__device__ inline float bfhi(unsigned u) { return __builtin_bit_cast(float, u & 0xffff0000u); }

// ---------------------------------------------------------------------------
// W[k,c] fp32 -> Wt[c,k] bf16, all three weights in one kernel.
// Also zeroes bcursor (must run before bucket_bin; it does, in stream order).
// ---------------------------------------------------------------------------
__global__ __launch_bounds__(256) void cvt_weights(
    const float* __restrict__ W1, const float* __restrict__ W2,
    const float* __restrict__ W3,
    unsigned short* __restrict__ W1t, unsigned short* __restrict__ W2t,
    unsigned short* __restrict__ W3t, int* __restrict__ bcursor)
{
    int g = blockIdx.x * 256 + threadIdx.x;
    if (g < NBUCK) bcursor[g] = 0;
    const float* W; unsigned short* Wt; int cols;
    if (g < 2048)      { W = W1; Wt = W1t; cols = 128; }
    else if (g < 4096) { W = W2; Wt = W2t; cols = 128; g -= 2048; }
    else if (g < 4608) { W = W3; Wt = W3t; cols = 32;  g -= 4096; }
    else return;
    int c  = g / 16;
    int k8 = (g % 16) * 8;
    unsigned up[4];
    #pragma unroll
    for (int j = 0; j < 4; ++j) {
        float a = W[(k8 + 2 * j) * cols + c];
        float b = W[(k8 + 2 * j + 1) * cols + c];
        up[j] = bf16rne(a) | (bf16rne(b) << 16);
    }
    uint4 u; u.x = up[0]; u.y = up[1]; u.z = up[2]; u.w = up[3];
    *(uint4*)(Wt + c * 128 + k8) = u;
}

// ---------------------------------------------------------------------------
// MFMA GEMM + fused attention coefficients — body shared by the standalone
// kernel and the fused sort|gemm kernel.
// ---------------------------------------------------------------------------
template<int NT, int NH, bool F32IN>
__device__ inline void gemm_body(
    int bid, const void* __restrict__ inv, const unsigned short* __restrict__ Wt,
    const float* __restrict__ a_s, const float* __restrict__ a_d,
    unsigned short* __restrict__ hout, float* __restrict__ asrc,
    float* __restrict__ adst)
{
    constexpr int COLS = NT * 16;
    constexpr int TPH  = NT / NH;        // tiles per head (2)
    const int lane = threadIdx.x & 63;
    const int wave = threadIdx.x >> 6;
    const int m    = lane & 15;
    const int quad = lane >> 4;
    const int n0   = bid * 64 + wave * 16;

    int arow = n0 + m; if (arow >= NN) arow = NN - 1;

    f32x4 acc[NT] = {};
    #pragma unroll
    for (int kq = 0; kq < 4; ++kq) {
        bf16x8 a;
        if constexpr (F32IN) {
            const float* ap = (const float*)inv + (long long)arow * 128 + quad * 8 + kq * 32;
            float4 v0 = *(const float4*)ap;
            float4 v1 = *(const float4*)(ap + 4);
            a[0] = (short)bf16rne(v0.x); a[1] = (short)bf16rne(v0.y);
            a[2] = (short)bf16rne(v0.z); a[3] = (short)bf16rne(v0.w);
            a[4] = (short)bf16rne(v1.x); a[5] = (short)bf16rne(v1.y);
            a[6] = (short)bf16rne(v1.z); a[7] = (short)bf16rne(v1.w);
        } else {
            a = *(const bf16x8*)((const unsigned short*)inv
                    + (long long)arow * 128 + quad * 8 + kq * 32);
        }
        #pragma unroll
        for (int t = 0; t < NT; ++t) {
            bf16x8 b = *(const bf16x8*)(Wt + (t * 16 + m) * 128 + kq * 32 + quad * 8);
            acc[t] = __builtin_amdgcn_mfma_f32_16x16x32_bf16(a, b, acc[t], 0, 0, 0);
        }
    }

    // ---- h store ----
    #pragma unroll
    for (int r = 0; r < 4; ++r) {
        int node = n0 + quad * 4 + r;
        if (node < NN) {
            #pragma unroll
            for (int t = 0; t < NT; ++t)
                hout[(long long)node * COLS + t * 16 + m] =
                    (unsigned short)bf16rne(acc[t][r]);
        }
    }

    // ---- fused alpha: per-head dots + 16-lane reduction ----
    float asv[NT], adv[NT];
    #pragma unroll
    for (int t = 0; t < NT; ++t) { asv[t] = a_s[t * 16 + m]; adv[t] = a_d[t * 16 + m]; }

    #pragma unroll
    for (int r = 0; r < 4; ++r) {
        const int node = n0 + quad * 4 + r;
        #pragma unroll
        for (int hh = 0; hh < NH; ++hh) {
            float ps = 0.f, pd = 0.f;
            #pragma unroll
            for (int q = 0; q < TPH; ++q) {
                int t = hh * TPH + q;
                ps = fmaf(acc[t][r], asv[t], ps);
                pd = fmaf(acc[t][r], adv[t], pd);
            }
            #pragma unroll
            for (int off = 8; off > 0; off >>= 1) {
                ps += __shfl_down(ps, off, 16);
                pd += __shfl_down(pd, off, 16);
            }
            if (m == 0 && node < NN) {
                asrc[node * NH + hh] = ps;
                adst[node * NH + hh] = pd;
            }
        }
    }

    // sentinel row: pads in sorted point to node NN -> exp(-1e30) == 0
    if (bid == 0 && threadIdx.x == 0) {
        #pragma unroll
        for (int hh = 0; hh < NH; ++hh) asrc[NN * NH + hh] = -1e30f;
    }
}

template<int NT, int NH, bool F32IN>
__global__ __launch_bounds__(256) void gemm_mfma(
    const void* __restrict__ inv, const unsigned short* __restrict__ Wt,
    const float* __restrict__ a_s, const float* __restrict__ a_d,
    unsigned short* __restrict__ hout, float* __restrict__ asrc,
    float* __restrict__ adst)
{
    gemm_body<NT, NH, F32IN>(blockIdx.x, inv, Wt, a_s, a_d, hout, asrc, adst);
}

// ---------------------------------------------------------------------------
// CSR build. pairs segmented per bucket (CAP each); sorted segmented per
// bucket (SCAP each); every node's range padded to a multiple of 4; pad
// slots hold sentinel node NN. rowp indexed by NODE (identity order —
// coalesced aggr output stores). Record: src:16 | dlocal:8 | bucket:8.
// ---------------------------------------------------------------------------
__global__ __launch_bounds__(256) void bucket_bin(
    const int* __restrict__ ei, int* __restrict__ bcursor,
    unsigned* __restrict__ pairs)
{
    __shared__ int cnt[NBUCK];
    __shared__ int scanex[NBUCK];
    __shared__ int base[NBUCK];
    __shared__ int cur[NBUCK];
    __shared__ unsigned stage[CH];       // 8 KB

    const int tid = threadIdx.x;
    const long long e0 = (long long)blockIdx.x * CH;
    cnt[tid] = 0;
    __syncthreads();

    unsigned rec[EPT]; int bk[EPT];
    #pragma unroll
    for (int j = 0; j < EPT; ++j) {
        long long e = e0 + tid + j * 256;
        bool valid = e < E2C;
        int ss = 0, dd = 0;
        if (valid) {
            if (e < EE) { ss = ei[e]; dd = ei[EE + e]; }
            else        { ss = dd = (int)(e - EE); }
        }
        int b = dd / BW;
        bk[j]  = valid ? b : -1;
        rec[j] = (unsigned)ss | ((unsigned)(dd - b * BW) << 16) | ((unsigned)b << 24);
        if (valid) atomicAdd(&cnt[b], 1);
    }
    __syncthreads();

    const int myc = cnt[tid];
    scanex[tid] = myc;
    __syncthreads();
    for (int off = 1; off < NBUCK; off <<= 1) {
        int t = (tid >= off) ? scanex[tid - off] : 0;
        __syncthreads();
        scanex[tid] += t;
        __syncthreads();
    }
    int excl = scanex[tid] - myc;
    __syncthreads();
    scanex[tid] = excl;
    cur[tid]    = excl;
    base[tid]   = atomicAdd(&bcursor[tid], myc);   // reserve chunk in segment
    __syncthreads();

    #pragma unroll
    for (int j = 0; j < EPT; ++j) {
        if (bk[j] >= 0) {
            int p = atomicAdd(&cur[bk[j]], 1);
            stage[p] = rec[j];
        }
    }
    __syncthreads();

    const int total = (e0 + CH <= E2C) ? CH : (int)(E2C - e0);
    for (int j = tid; j < total; j += 256) {
        unsigned p = stage[j];
        int b = (int)(p >> 24);
        pairs[(size_t)b * CAP + base[b] + (j - scanex[b])] = p;
    }
}

__device__ inline void sort_body(
    int b, const int* __restrict__ bcursor, const unsigned* __restrict__ pairs,
    int2* __restrict__ rowp, unsigned short* __restrict__ sorted_src)
{
    __shared__ int deg[256];
    __shared__ int scn[256];
    __shared__ int cur[256];
    const int n0 = b * BW;
    const int n1 = (n0 + BW < NN) ? n0 + BW : NN;
    const int nloc = n1 - n0;
    const int tid = threadIdx.x;
    const int mycnt = bcursor[b];
    const unsigned* seg = pairs + (size_t)b * CAP;
    const int base = b * SCAP;

    deg[tid] = 0;
    __syncthreads();
    for (int i = tid; i < mycnt; i += 256)
        atomicAdd(&deg[(seg[i] >> 16) & 0xff], 1);
    __syncthreads();

    const int pv = (deg[tid] + 3) & ~3;            // degree padded to mult of 4
    scn[tid] = pv;
    __syncthreads();
    for (int off = 1; off < 256; off <<= 1) {
        int t = (tid >= off) ? scn[tid - off] : 0;
        __syncthreads();
        scn[tid] += t;
        __syncthreads();
    }
    const int totalp = scn[255];
    const int pexcl  = scn[tid] - pv;
    cur[tid] = base + pexcl;
    if (tid < nloc) rowp[n0 + tid] = make_int2(base + pexcl, base + pexcl + pv);
    __syncthreads();

    // sentinel-fill padded extent (+8 prefetch slack, capped at own segment),
    // then scatter real entries over it
    int lim = totalp + 8; if (lim > SCAP) lim = SCAP;
    for (int i = tid; i < lim; i += 256)
        sorted_src[base + i] = (unsigned short)NN;
    if (b == NBUCK - 1 && tid < 8)
        sorted_src[NBUCK * SCAP + tid] = (unsigned short)NN;   // global slack
    __syncthreads();
    for (int i = tid; i < mycnt; i += 256) {
        unsigned p = seg[i];
        int pos = atomicAdd(&cur[(p >> 16) & 0xff], 1);
        sorted_src[pos] = (unsigned short)(p & 0xffff);
    }
}

// ---------------------------------------------------------------------------
// FUSED dispatch: bucket_sort (blocks 0..NBUCK-1) || layer-1 GEMM (rest).
// The two are mutually independent: sort needs only bucket_bin's output;
// gemm1 needs only x and W1t (both ready). Overlapping them hides the
// CSR-sort time entirely under the layer-1 GEMM.
// ---------------------------------------------------------------------------
template<int NT, int NH, bool F32IN>
__global__ __launch_bounds__(256) void sort_gemm(
    const int* __restrict__ bcursor, const unsigned* __restrict__ pairs,
    int2* __restrict__ rowp, unsigned short* __restrict__ sorted_src,
    const void* __restrict__ inv, const unsigned short* __restrict__ Wt,
    const float* __restrict__ a_s, const float* __restrict__ a_d,
    unsigned short* __restrict__ hout, float* __restrict__ asrc,
    float* __restrict__ adst)
{
    if (blockIdx.x < NBUCK)
        sort_body(blockIdx.x, bcursor, pairs, rowp, sorted_src);
    else
        gemm_body<NT, NH, F32IN>(blockIdx.x - NBUCK, inv, Wt, a_s, a_d,
                                 hout, asrc, adst);
}

// ---------------------------------------------------------------------------
// CSR gather aggregation over bf16 h: padded mask-free 4-deep batches.
// One aligned ushort4 index load per batch, prefetched one batch ahead;
// pads are sentinel node NN (w = 0). 8 channels/lane, COLS/8 lanes/node.
// Identity node order: rowp[d], coalesced output stores (round-0 proven).
// ---------------------------------------------------------------------------
template<int COLS, int NH, bool DO_ELU, bool OUTBF>
__global__ __launch_bounds__(256) void aggr_csr(
    const int2* __restrict__ rowp, const unsigned short* __restrict__ sorted_src,
    const unsigned short* __restrict__ hin,
    const float* __restrict__ asrc, const float* __restrict__ adst,
    const float* __restrict__ bias, void* __restrict__ outv)
{
    constexpr int TPN = COLS / 8;             // lanes per node: 16 or 4
    constexpr int USTR = COLS / 2;            // uints per h row
    int t = blockIdx.x * 256 + threadIdx.x;
    int d = t / TPN;
    int lc = t % TPN;                         // owns channels 8*lc .. 8*lc+7
    if (d >= NN) return;
    const int cc = lc * 8;
    const int head = cc / 32;                 // 0..NH-1
    const float ad = adst[d * NH + head];
    const int2 be = rowp[d];
    const int beg = be.x, end = be.y;         // 4-aligned; deg >= 1 => beg < end
    const uint* hp = (const uint*)hin + cc / 2;

    float num[8] = {};
    float den = 0.f;

    ushort4 sv = *(const ushort4*)&sorted_src[beg];
    for (int i = beg; i < end; i += 4) {
        ushort4 nx = *(const ushort4*)&sorted_src[i + 4];   // segment slack
        const int s[4] = {sv.x, sv.y, sv.z, sv.w};
        float a[4];
        uint4 Hv[4];
        #pragma unroll
        for (int j = 0; j < 4; ++j) a[j] = asrc[s[j] * NH + head];
        #pragma unroll
        for (int j = 0; j < 4; ++j)
            Hv[j] = *(const uint4*)&hp[(long long)s[j] * USTR];
        #pragma unroll
        for (int j = 0; j < 4; ++j) {
            float l = a[j] + ad; l = l > 0.f ? l : 0.2f * l;
            float w = __builtin_expf(l);
            den += w;
            num[0] = fmaf(w, bflo(Hv[j].x), num[0]); num[1] = fmaf(w, bfhi(Hv[j].x), num[1]);
            num[2] = fmaf(w, bflo(Hv[j].y), num[2]); num[3] = fmaf(w, bfhi(Hv[j].y), num[3]);
            num[4] = fmaf(w, bflo(Hv[j].z), num[4]); num[5] = fmaf(w, bfhi(Hv[j].z), num[5]);
            num[6] = fmaf(w, bflo(Hv[j].w), num[6]); num[7] = fmaf(w, bfhi(Hv[j].w), num[7]);
        }
        sv = nx;
    }

    float inv = 1.f / (den + 1e-16f);
    float v[8];
    #pragma unroll
    for (int j = 0; j < 8; ++j) {
        v[j] = num[j] * inv + bias[cc + j];
        if (DO_ELU) v[j] = v[j] > 0.f ? v[j] : expm1f(v[j]);
    }
    if constexpr (OUTBF) {
        uint4 u;
        u.x = bf16rne(v[0]) | (bf16rne(v[1]) << 16);
        u.y = bf16rne(v[2]) | (bf16rne(v[3]) << 16);
        u.z = bf16rne(v[4]) | (bf16rne(v[5]) << 16);
        u.w = bf16rne(v[6]) | (bf16rne(v[7]) << 16);
        *(uint4*)((unsigned short*)outv + (long long)d * COLS + cc) = u;
    } else {
        float4 o0 = {v[0], v[1], v[2], v[3]};
        float4 o1 = {v[4], v[5], v[6], v[7]};
        float* out = (float*)outv;
        *(float4*)&out[(long long)d * COLS + cc]     = o0;
        *(float4*)&out[(long long)d * COLS + cc + 4] = o1;
    }
}

// ---------------------------------------------------------------------------
extern "C" void kernel_launch(void* const* d_in, const int* in_sizes, int n_in,
                              void* d_out, int out_size, void* d_ws, size_t ws_size,
                              hipStream_t stream)
{
    const float* x   = (const float*)d_in[0];
    const int*   ei  = (const int*)  d_in[1];
    const float* W1  = (const float*)d_in[2];
    const float* as1 = (const float*)d_in[3];
    const float* ad1 = (const float*)d_in[4];
    const float* b1  = (const float*)d_in[5];
    const float* W2  = (const float*)d_in[6];
    const float* as2 = (const float*)d_in[7];
    const float* ad2 = (const float*)d_in[8];
    const float* b2  = (const float*)d_in[9];
    const float* W3  = (const float*)d_in[10];
    const float* as3 = (const float*)d_in[11];
    const float* ad3 = (const float*)d_in[12];
    const float* b3  = (const float*)d_in[13];
    float* out = (float*)d_out;

    // workspace layout (16B-aligned bf16 buffers first). H16 has sentinel row.
    unsigned short* H16 = (unsigned short*)d_ws;          // (N+1)*128 bf16
    unsigned short* O16 = H16 + (size_t)(NN + 1) * 128;   // N*128 bf16
    unsigned short* P16 = O16 + (size_t)NN * 128;         // N*128 bf16
    unsigned short* W1t = P16 + (size_t)NN * 128;         // 128*128 bf16
    unsigned short* W2t = W1t + 128 * 128;
    unsigned short* W3t = W2t + 128 * 128;                // 32*128
    float* ASRC = (float*)(W3t + 32 * 128);               // (N+1)*4
    float* ADST = ASRC + (size_t)(NN + 1) * 4;            // N*4
    int2* rowp  = (int2*)(ADST + (size_t)NN * 4);         // NN int2 (node-indexed)
    unsigned short* sorted = (unsigned short*)(rowp + NN);         // NBUCK*SCAP+8 u16
    int* bcursor = (int*)(sorted + (size_t)NBUCK * SCAP + 8);      // NBUCK
    size_t off = ((size_t)(bcursor + NBUCK) - (size_t)d_ws + 15) & ~(size_t)15;
    unsigned* pairs = (unsigned*)((char*)d_ws + off);     // NBUCK*CAP u32 (4 MB)

    const int gCvtW    = (4608 + 255) / 256;             // 18
    const int gGemm    = (NN + 63) / 64;                 // 782
    const int gSortG   = NBUCK + gGemm;                  // 1038
    const int gAggr128 = (NN * 16 + 255) / 256;          // 3125
    const int gAggr32  = (NN * 4 + 255) / 256;           // 782

    // ---- weight conversion (+ bcursor zeroing), then CSR bin ----
    cvt_weights<<<gCvtW, 256, 0, stream>>>(W1, W2, W3, W1t, W2t, W3t, bcursor);
    bucket_bin<<<NB_B, 256, 0, stream>>>(ei, bcursor, pairs);

    // ---- fused: CSR sort || layer-1 GEMM (fp32 x read directly) ----
    sort_gemm<8, 4, true><<<gSortG, 256, 0, stream>>>(
        bcursor, pairs, rowp, sorted, x, W1t, as1, ad1, H16, ASRC, ADST);
    aggr_csr<128, 4, true, true><<<gAggr128, 256, 0, stream>>>(
        rowp, sorted, H16, ASRC, ADST, b1, O16);

    // ---- layer 2 (128 -> 4x32 concat, ELU) ----
    gemm_mfma<8, 4, false><<<gGemm, 256, 0, stream>>>(O16, W2t, as2, ad2, H16, ASRC, ADST);
    aggr_csr<128, 4, true, true><<<gAggr128, 256, 0, stream>>>(
        rowp, sorted, H16, ASRC, ADST, b2, P16);

    // ---- layer 3 (128 -> 32, 1 head, no concat) ----
    gemm_mfma<2, 1, false><<<gGemm, 256, 0, stream>>>(P16, W3t, as3, ad3, H16, ASRC, ADST);
    aggr_csr<32, 1, false, false><<<gAggr32, 256, 0, stream>>>(
        rowp, sorted, H16, ASRC, ADST, b3, out);
}

// Round 6
// 258.486 us; speedup vs baseline: 1.0852x; 1.0505x over previous
//
#include <hip/hip_runtime.h>
#include <cmath>

constexpr int NN  = 50000;          // nodes
constexpr int EE  = 800000;         // raw edges
constexpr int E2C = EE + NN;        // edges incl. self loops = 850000

// bucketed counting sort params
constexpr int NBUCK = 256;          // dst buckets
constexpr int BW    = 196;          // bucket width: 196*256 = 50176 >= NN
constexpr int EPT   = 8;            // edges per thread (bin)
constexpr int CH    = 256 * EPT;    // 2048 edges per block
constexpr int NB_B  = (E2C + CH - 1) / CH;  // 416 blocks
constexpr int CAP   = 4096;         // per-bucket pairs capacity
constexpr int SCAP  = 5120;         // per-bucket padded sorted capacity
constexpr int G1ALL = (NN + 63) / 64;       // 782 gemm1 blocks
constexpr int G1A   = 391;                  // gemm1 blocks co-run with bin

using bf16x8 = __attribute__((ext_vector_type(8))) short;
using f32x4  = __attribute__((ext_vector_type(4))) float;

// bf16 helpers (storage bf16, math fp32)
__device__ inline unsigned bf16rne(float f) {
    unsigned u = __builtin_bit_cast(unsigned, f);
    return (u + 0x7fffu + ((u >> 16) & 1u)) >> 16;     // round-nearest-even
}
__device__ inline float bflo(unsigned u) { return __builtin_bit_cast(float, u << 16); }
__device__ inline float bfhi(unsigned u) { return __builtin_bit_cast(float, u & 0xffff0000u); }

// ---------------------------------------------------------------------------
// W[k,c] fp32 -> Wt[c,k] bf16 (all three), + zero bcursor, + write alpha
// sentinels (-1e30 at node NN) and zero h sentinel rows.
// ---------------------------------------------------------------------------
__global__ __launch_bounds__(256) void cvt_weights(
    const float* __restrict__ W1, const float* __restrict__ W2,
    const float* __restrict__ W3,
    unsigned short* __restrict__ W1t, unsigned short* __restrict__ W2t,
    unsigned short* __restrict__ W3t, int* __restrict__ bcursor,
    float* __restrict__ AS1, float* __restrict__ AS2, float* __restrict__ AS3,
    unsigned short* __restrict__ H1, unsigned short* __restrict__ H2,
    unsigned short* __restrict__ H3)
{
    int g = blockIdx.x * 256 + threadIdx.x;
    if (g < NBUCK) bcursor[g] = 0;
    if (g < 4) { AS1[NN * 4 + g] = -1e30f; AS2[NN * 4 + g] = -1e30f; }
    if (g == 4) AS3[NN] = -1e30f;
    if (g < 128) { H1[(size_t)NN * 128 + g] = 0; H2[(size_t)NN * 128 + g] = 0; }
    if (g < 32)  H3[(size_t)NN * 32 + g] = 0;

    const float* W; unsigned short* Wt; int cols;
    if (g < 2048)      { W = W1; Wt = W1t; cols = 128; }
    else if (g < 4096) { W = W2; Wt = W2t; cols = 128; g -= 2048; }
    else if (g < 4608) { W = W3; Wt = W3t; cols = 32;  g -= 4096; }
    else return;
    int c  = g / 16;
    int k8 = (g % 16) * 8;
    unsigned up[4];
    #pragma unroll
    for (int j = 0; j < 4; ++j) {
        float a = W[(k8 + 2 * j) * cols + c];
        float b = W[(k8 + 2 * j + 1) * cols + c];
        up[j] = bf16rne(a) | (bf16rne(b) << 16);
    }
    uint4 u; u.x = up[0]; u.y = up[1]; u.z = up[2]; u.w = up[3];
    *(uint4*)(Wt + c * 128 + k8) = u;
}

// ---------------------------------------------------------------------------
// Layer-1 MFMA GEMM body (64 nodes per bid) + fused alpha dots.
// ---------------------------------------------------------------------------
template<int NT, int NH, bool F32IN>
__device__ inline void gemm_body(
    int bid, const void* __restrict__ inv, const unsigned short* __restrict__ Wt,
    const float* __restrict__ a_s, const float* __restrict__ a_d,
    unsigned short* __restrict__ hout, float* __restrict__ asrc,
    float* __restrict__ adst)
{
    constexpr int COLS = NT * 16;
    constexpr int TPH  = NT / NH;
    const int lane = threadIdx.x & 63;
    const int wave = threadIdx.x >> 6;
    const int m    = lane & 15;
    const int quad = lane >> 4;
    const int n0   = bid * 64 + wave * 16;

    int arow = n0 + m; if (arow >= NN) arow = NN - 1;

    f32x4 acc[NT] = {};
    #pragma unroll
    for (int kq = 0; kq < 4; ++kq) {
        bf16x8 a;
        if constexpr (F32IN) {
            const float* ap = (const float*)inv + (long long)arow * 128 + quad * 8 + kq * 32;
            float4 v0 = *(const float4*)ap;
            float4 v1 = *(const float4*)(ap + 4);
            a[0] = (short)bf16rne(v0.x); a[1] = (short)bf16rne(v0.y);
            a[2] = (short)bf16rne(v0.z); a[3] = (short)bf16rne(v0.w);
            a[4] = (short)bf16rne(v1.x); a[5] = (short)bf16rne(v1.y);
            a[6] = (short)bf16rne(v1.z); a[7] = (short)bf16rne(v1.w);
        } else {
            a = *(const bf16x8*)((const unsigned short*)inv
                    + (long long)arow * 128 + quad * 8 + kq * 32);
        }
        #pragma unroll
        for (int t = 0; t < NT; ++t) {
            bf16x8 b = *(const bf16x8*)(Wt + (t * 16 + m) * 128 + kq * 32 + quad * 8);
            acc[t] = __builtin_amdgcn_mfma_f32_16x16x32_bf16(a, b, acc[t], 0, 0, 0);
        }
    }

    #pragma unroll
    for (int r = 0; r < 4; ++r) {
        int node = n0 + quad * 4 + r;
        if (node < NN) {
            #pragma unroll
            for (int t = 0; t < NT; ++t)
                hout[(long long)node * COLS + t * 16 + m] =
                    (unsigned short)bf16rne(acc[t][r]);
        }
    }

    float asv[NT], adv[NT];
    #pragma unroll
    for (int t = 0; t < NT; ++t) { asv[t] = a_s[t * 16 + m]; adv[t] = a_d[t * 16 + m]; }

    #pragma unroll
    for (int r = 0; r < 4; ++r) {
        const int node = n0 + quad * 4 + r;
        #pragma unroll
        for (int hh = 0; hh < NH; ++hh) {
            float ps = 0.f, pd = 0.f;
            #pragma unroll
            for (int q = 0; q < TPH; ++q) {
                int t = hh * TPH + q;
                ps = fmaf(acc[t][r], asv[t], ps);
                pd = fmaf(acc[t][r], adv[t], pd);
            }
            #pragma unroll
            for (int off = 8; off > 0; off >>= 1) {
                ps += __shfl_down(ps, off, 16);
                pd += __shfl_down(pd, off, 16);
            }
            if (m == 0 && node < NN) {
                asrc[node * NH + hh] = ps;
                adst[node * NH + hh] = pd;
            }
        }
    }
}

// ---------------------------------------------------------------------------
// CSR build bodies. Record: src:16 | dlocal:8 | bucket:8.
// ---------------------------------------------------------------------------
__device__ inline void bin_body(
    int bid, const int* __restrict__ ei, int* __restrict__ bcursor,
    unsigned* __restrict__ pairs)
{
    __shared__ int cnt[NBUCK];
    __shared__ int scanex[NBUCK];
    __shared__ int base[NBUCK];
    __shared__ int cur[NBUCK];
    __shared__ unsigned stage[CH];       // 8 KB

    const int tid = threadIdx.x;
    const long long e0 = (long long)bid * CH;
    cnt[tid] = 0;
    __syncthreads();

    unsigned rec[EPT]; int bk[EPT];
    #pragma unroll
    for (int j = 0; j < EPT; ++j) {
        long long e = e0 + tid + j * 256;
        bool valid = e < E2C;
        int ss = 0, dd = 0;
        if (valid) {
            if (e < EE) { ss = ei[e]; dd = ei[EE + e]; }
            else        { ss = dd = (int)(e - EE); }
        }
        int b = dd / BW;
        bk[j]  = valid ? b : -1;
        rec[j] = (unsigned)ss | ((unsigned)(dd - b * BW) << 16) | ((unsigned)b << 24);
        if (valid) atomicAdd(&cnt[b], 1);
    }
    __syncthreads();

    const int myc = cnt[tid];
    scanex[tid] = myc;
    __syncthreads();
    for (int off = 1; off < NBUCK; off <<= 1) {
        int t = (tid >= off) ? scanex[tid - off] : 0;
        __syncthreads();
        scanex[tid] += t;
        __syncthreads();
    }
    int excl = scanex[tid] - myc;
    __syncthreads();
    scanex[tid] = excl;
    cur[tid]    = excl;
    base[tid]   = atomicAdd(&bcursor[tid], myc);
    __syncthreads();

    #pragma unroll
    for (int j = 0; j < EPT; ++j) {
        if (bk[j] >= 0) {
            int p = atomicAdd(&cur[bk[j]], 1);
            stage[p] = rec[j];
        }
    }
    __syncthreads();

    const int total = (e0 + CH <= E2C) ? CH : (int)(E2C - e0);
    for (int j = tid; j < total; j += 256) {
        unsigned p = stage[j];
        int b = (int)(p >> 24);
        pairs[(size_t)b * CAP + base[b] + (j - scanex[b])] = p;
    }
}

__device__ inline void sort_body(
    int b, const int* __restrict__ bcursor, const unsigned* __restrict__ pairs,
    int2* __restrict__ rowp, unsigned short* __restrict__ sorted_src)
{
    __shared__ int deg[256];
    __shared__ int scn[256];
    __shared__ int cur[256];
    const int n0 = b * BW;
    const int n1 = (n0 + BW < NN) ? n0 + BW : NN;
    const int nloc = n1 - n0;
    const int tid = threadIdx.x;
    const int mycnt = bcursor[b];
    const unsigned* seg = pairs + (size_t)b * CAP;
    const int base = b * SCAP;

    deg[tid] = 0;
    __syncthreads();
    for (int i = tid; i < mycnt; i += 256)
        atomicAdd(&deg[(seg[i] >> 16) & 0xff], 1);
    __syncthreads();

    const int pv = (deg[tid] + 3) & ~3;
    scn[tid] = pv;
    __syncthreads();
    for (int off = 1; off < 256; off <<= 1) {
        int t = (tid >= off) ? scn[tid - off] : 0;
        __syncthreads();
        scn[tid] += t;
        __syncthreads();
    }
    const int totalp = scn[255];
    const int pexcl  = scn[tid] - pv;
    cur[tid] = base + pexcl;
    if (tid < nloc) rowp[n0 + tid] = make_int2(base + pexcl, base + pexcl + pv);
    __syncthreads();

    int lim = totalp + 8; if (lim > SCAP) lim = SCAP;
    for (int i = tid; i < lim; i += 256)
        sorted_src[base + i] = (unsigned short)NN;
    if (b == NBUCK - 1 && tid < 8)
        sorted_src[NBUCK * SCAP + tid] = (unsigned short)NN;
    __syncthreads();
    for (int i = tid; i < mycnt; i += 256) {
        unsigned p = seg[i];
        int pos = atomicAdd(&cur[(p >> 16) & 0xff], 1);
        sorted_src[pos] = (unsigned short)(p & 0xffff);
    }
}

// ---------------------------------------------------------------------------
// Overlap dispatches: [bin || gemm1 first half], [sort || gemm1 second half]
// ---------------------------------------------------------------------------
__global__ __launch_bounds__(256) void bin_gemm(
    const int* __restrict__ ei, int* __restrict__ bcursor,
    unsigned* __restrict__ pairs,
    const float* __restrict__ x, const unsigned short* __restrict__ Wt,
    const float* __restrict__ a_s, const float* __restrict__ a_d,
    unsigned short* __restrict__ hout, float* __restrict__ asrc,
    float* __restrict__ adst)
{
    if (blockIdx.x < NB_B)
        bin_body(blockIdx.x, ei, bcursor, pairs);
    else
        gemm_body<8, 4, true>(blockIdx.x - NB_B, x, Wt, a_s, a_d, hout, asrc, adst);
}

__global__ __launch_bounds__(256) void sort_gemm(
    const int* __restrict__ bcursor, const unsigned* __restrict__ pairs,
    int2* __restrict__ rowp, unsigned short* __restrict__ sorted_src,
    const float* __restrict__ x, const unsigned short* __restrict__ Wt,
    const float* __restrict__ a_s, const float* __restrict__ a_d,
    unsigned short* __restrict__ hout, float* __restrict__ asrc,
    float* __restrict__ adst)
{
    if (blockIdx.x < NBUCK)
        sort_body(blockIdx.x, bcursor, pairs, rowp, sorted_src);
    else
        gemm_body<8, 4, true>(blockIdx.x - NBUCK + G1A, x, Wt, a_s, a_d,
                              hout, asrc, adst);
}

// ---------------------------------------------------------------------------
// Per-node-channel-group CSR aggregation core (round-0 proven structure):
// padded mask-free 4-deep batches, one ushort4 index load per batch
// prefetched one batch ahead; pads -> sentinel node NN (weight exp(-1e30)=0).
// Produces the post-bias (and optional ELU) layer output v[8] in registers.
// ---------------------------------------------------------------------------
template<int COLS, int NH, bool DO_ELU>
__device__ inline void aggr_node(
    int d, int lc,
    const int2* __restrict__ rowp, const unsigned short* __restrict__ sorted_src,
    const unsigned short* __restrict__ hin,
    const float* __restrict__ asrc, const float* __restrict__ adst,
    const float* __restrict__ bias, float v[8])
{
    constexpr int USTR = COLS / 2;            // uints per h row
    const int cc = lc * 8;
    const int head = cc / 32;
    const float ad = adst[d * NH + head];
    const int2 be = rowp[d];
    const int beg = be.x, end = be.y;         // 4-aligned; deg >= 1
    const uint* hp = (const uint*)hin + cc / 2;

    float num[8] = {};
    float den = 0.f;

    ushort4 sv = *(const ushort4*)&sorted_src[beg];
    for (int i = beg; i < end; i += 4) {
        ushort4 nx = *(const ushort4*)&sorted_src[i + 4];   // slack sentinel-filled
        const int s[4] = {sv.x, sv.y, sv.z, sv.w};
        float a[4];
        uint4 Hv[4];
        #pragma unroll
        for (int j = 0; j < 4; ++j) a[j] = asrc[s[j] * NH + head];
        #pragma unroll
        for (int j = 0; j < 4; ++j)
            Hv[j] = *(const uint4*)&hp[(long long)s[j] * USTR];
        #pragma unroll
        for (int j = 0; j < 4; ++j) {
            float l = a[j] + ad; l = l > 0.f ? l : 0.2f * l;
            float w = __builtin_expf(l);
            den += w;
            num[0] = fmaf(w, bflo(Hv[j].x), num[0]); num[1] = fmaf(w, bfhi(Hv[j].x), num[1]);
            num[2] = fmaf(w, bflo(Hv[j].y), num[2]); num[3] = fmaf(w, bfhi(Hv[j].y), num[3]);
            num[4] = fmaf(w, bflo(Hv[j].z), num[4]); num[5] = fmaf(w, bfhi(Hv[j].z), num[5]);
            num[6] = fmaf(w, bflo(Hv[j].w), num[6]); num[7] = fmaf(w, bfhi(Hv[j].w), num[7]);
        }
        sv = nx;
    }

    float inv = 1.f / (den + 1e-16f);
    #pragma unroll
    for (int j = 0; j < 8; ++j) {
        v[j] = num[j] * inv + bias[cc + j];
        if (DO_ELU) v[j] = v[j] > 0.f ? v[j] : expm1f(v[j]);
    }
}

// ---------------------------------------------------------------------------
// FUSED aggregation + next-layer mini-GEMM. One 256-thread block owns all
// 128 channels of 16 consecutive nodes — exactly one 16-row MFMA A-tile.
// After the aggr epilogue the block stages the 16x128 bf16 tile in LDS
// (XOR-swizzled: byte_col ^= (row&7)<<4, conflict-minimal for both the
// ds_write_b128 and the per-(m,quad) ds_read_b128 fragment loads) and runs
// the next layer's GEMM for those rows: deletes the standalone gemm dispatch,
// the intermediate h roundtrip through HBM/L3, and hides MFMA under gather
// latency. NT_OUT=8 (128 cols, 2 tiles/wave, head=wave) or NT_OUT=2
// (32 cols, wave 0 only).
// ---------------------------------------------------------------------------
template<int NT_OUT, int NH_OUT>
__global__ __launch_bounds__(256) void aggr_gemm(
    const int2* __restrict__ rowp, const unsigned short* __restrict__ sorted_src,
    const unsigned short* __restrict__ hin,
    const float* __restrict__ asrc_in, const float* __restrict__ adst_in,
    const float* __restrict__ bias,
    const unsigned short* __restrict__ Wt,
    const float* __restrict__ a_s, const float* __restrict__ a_d,
    unsigned short* __restrict__ hout, float* __restrict__ asrc_out,
    float* __restrict__ adst_out)
{
    __shared__ unsigned short lds_h[16 * 128];   // 4 KB
    const int tid = threadIdx.x;
    const int row = tid / 16;                    // local node 0..15
    const int lc  = tid % 16;
    const int d   = blockIdx.x * 16 + row;       // grid exact: d < NN always

    float v[8];
    aggr_node<128, 4, true>(d, lc, rowp, sorted_src, hin, asrc_in, adst_in,
                            bias, v);

    // stage post-ELU output tile to LDS as bf16, swizzled
    uint4 u;
    u.x = bf16rne(v[0]) | (bf16rne(v[1]) << 16);
    u.y = bf16rne(v[2]) | (bf16rne(v[3]) << 16);
    u.z = bf16rne(v[4]) | (bf16rne(v[5]) << 16);
    u.w = bf16rne(v[6]) | (bf16rne(v[7]) << 16);
    *(uint4*)((char*)lds_h + row * 256 + ((lc * 16) ^ ((row & 7) << 4))) = u;
    __syncthreads();

    // ---- mini-GEMM: 16 nodes x 128k @ Wt ----
    const int lane = tid & 63;
    const int wave = tid >> 6;
    const int m    = lane & 15;
    const int quad = lane >> 4;
    int t0;
    if constexpr (NT_OUT == 8) t0 = wave * 2;
    else { if (wave != 0) return; t0 = 0; }

    f32x4 acc[2] = {};
    #pragma unroll
    for (int kq = 0; kq < 4; ++kq) {
        int colb = (quad * 16 + kq * 64) ^ ((m & 7) << 4);
        bf16x8 a = *(const bf16x8*)((const char*)lds_h + m * 256 + colb);
        #pragma unroll
        for (int tt = 0; tt < 2; ++tt) {
            bf16x8 b = *(const bf16x8*)(Wt + ((t0 + tt) * 16 + m) * 128
                                        + kq * 32 + quad * 8);
            acc[tt] = __builtin_amdgcn_mfma_f32_16x16x32_bf16(a, b, acc[tt], 0, 0, 0);
        }
    }

    constexpr int COLS_OUT = NT_OUT * 16;
    const int head = t0 / (NT_OUT / NH_OUT);
    const int n0   = blockIdx.x * 16;
    float asv[2], adv[2];
    #pragma unroll
    for (int tt = 0; tt < 2; ++tt) {
        asv[tt] = a_s[(t0 + tt) * 16 + m];
        adv[tt] = a_d[(t0 + tt) * 16 + m];
    }

    #pragma unroll
    for (int r = 0; r < 4; ++r) {
        const int node = n0 + quad * 4 + r;      // always < NN
        #pragma unroll
        for (int tt = 0; tt < 2; ++tt)
            hout[(long long)node * COLS_OUT + (t0 + tt) * 16 + m] =
                (unsigned short)bf16rne(acc[tt][r]);
        float ps = acc[0][r] * asv[0];
        ps = fmaf(acc[1][r], asv[1], ps);
        float pd = acc[0][r] * adv[0];
        pd = fmaf(acc[1][r], adv[1], pd);
        #pragma unroll
        for (int off = 8; off > 0; off >>= 1) {
            ps += __shfl_down(ps, off, 16);
            pd += __shfl_down(pd, off, 16);
        }
        if (m == 0) {
            asrc_out[node * NH_OUT + head] = ps;
            adst_out[node * NH_OUT + head] = pd;
        }
    }
}

// ---------------------------------------------------------------------------
// Final standalone aggregation (layer 3): fp32 output to d_out.
// ---------------------------------------------------------------------------
template<int COLS, int NH>
__global__ __launch_bounds__(256) void aggr_final(
    const int2* __restrict__ rowp, const unsigned short* __restrict__ sorted_src,
    const unsigned short* __restrict__ hin,
    const float* __restrict__ asrc, const float* __restrict__ adst,
    const float* __restrict__ bias, float* __restrict__ out)
{
    constexpr int TPN = COLS / 8;
    int t = blockIdx.x * 256 + threadIdx.x;
    int d = t / TPN;
    int lc = t % TPN;
    if (d >= NN) return;
    float v[8];
    aggr_node<COLS, NH, false>(d, lc, rowp, sorted_src, hin, asrc, adst, bias, v);
    float4 o0 = {v[0], v[1], v[2], v[3]};
    float4 o1 = {v[4], v[5], v[6], v[7]};
    *(float4*)&out[(long long)d * COLS + lc * 8]     = o0;
    *(float4*)&out[(long long)d * COLS + lc * 8 + 4] = o1;
}

// ---------------------------------------------------------------------------
extern "C" void kernel_launch(void* const* d_in, const int* in_sizes, int n_in,
                              void* d_out, int out_size, void* d_ws, size_t ws_size,
                              hipStream_t stream)
{
    const float* x   = (const float*)d_in[0];
    const int*   ei  = (const int*)  d_in[1];
    const float* W1  = (const float*)d_in[2];
    const float* as1 = (const float*)d_in[3];
    const float* ad1 = (const float*)d_in[4];
    const float* b1  = (const float*)d_in[5];
    const float* W2  = (const float*)d_in[6];
    const float* as2 = (const float*)d_in[7];
    const float* ad2 = (const float*)d_in[8];
    const float* b2  = (const float*)d_in[9];
    const float* W3  = (const float*)d_in[10];
    const float* as3 = (const float*)d_in[11];
    const float* ad3 = (const float*)d_in[12];
    const float* b3  = (const float*)d_in[13];
    float* out = (float*)d_out;

    // workspace layout (16B-aligned bf16 buffers first); each h has a
    // zeroed sentinel row NN.
    unsigned short* H1  = (unsigned short*)d_ws;          // (N+1)*128 bf16
    unsigned short* H2  = H1 + (size_t)(NN + 1) * 128;    // (N+1)*128 bf16
    unsigned short* H3  = H2 + (size_t)(NN + 1) * 128;    // (N+1)*32 bf16
    unsigned short* W1t = H3 + (size_t)(NN + 1) * 32;     // 128*128 bf16
    unsigned short* W2t = W1t + 128 * 128;
    unsigned short* W3t = W2t + 128 * 128;                // 32*128
    float* AS1 = (float*)(W3t + 32 * 128);                // (N+1)*4
    float* AD1 = AS1 + (size_t)(NN + 1) * 4;              // N*4
    float* AS2 = AD1 + (size_t)NN * 4;                    // (N+1)*4
    float* AD2 = AS2 + (size_t)(NN + 1) * 4;              // N*4
    float* AS3 = AD2 + (size_t)NN * 4;                    // (N+1)
    float* AD3 = AS3 + (size_t)(NN + 1);                  // N
    int2* rowp = (int2*)(AD3 + NN);                       // NN int2
    unsigned short* sorted = (unsigned short*)(rowp + NN);         // NBUCK*SCAP+8
    int* bcursor = (int*)(sorted + (size_t)NBUCK * SCAP + 8);      // NBUCK
    size_t off = ((size_t)(bcursor + NBUCK) - (size_t)d_ws + 15) & ~(size_t)15;
    unsigned* pairs = (unsigned*)((char*)d_ws + off);     // NBUCK*CAP u32 (4 MB)

    const int gCvtW  = (4608 + 255) / 256;               // 18
    const int gBinG  = NB_B + G1A;                       // 416 + 391
    const int gSortG = NBUCK + (G1ALL - G1A);            // 256 + 391
    const int gFused = NN / 16;                          // 3125 (exact)
    const int gAggr3 = (NN * 4 + 255) / 256;             // 782

    // 1) weights + sentinels
    cvt_weights<<<gCvtW, 256, 0, stream>>>(W1, W2, W3, W1t, W2t, W3t, bcursor,
                                           AS1, AS2, AS3, H1, H2, H3);
    // 2) edge binning || layer-1 GEMM (first half)
    bin_gemm<<<gBinG, 256, 0, stream>>>(ei, bcursor, pairs,
                                        x, W1t, as1, ad1, H1, AS1, AD1);
    // 3) CSR sort || layer-1 GEMM (second half)
    sort_gemm<<<gSortG, 256, 0, stream>>>(bcursor, pairs, rowp, sorted,
                                          x, W1t, as1, ad1, H1, AS1, AD1);
    // 4) aggr layer 1 + GEMM layer 2 (fused)
    aggr_gemm<8, 4><<<gFused, 256, 0, stream>>>(
        rowp, sorted, H1, AS1, AD1, b1, W2t, as2, ad2, H2, AS2, AD2);
    // 5) aggr layer 2 + GEMM layer 3 (fused)
    aggr_gemm<2, 1><<<gFused, 256, 0, stream>>>(
        rowp, sorted, H2, AS2, AD2, b2, W3t, as3, ad3, H3, AS3, AD3);
    // 6) final aggr layer 3 -> fp32 output
    aggr_final<32, 1><<<gAggr3, 256, 0, stream>>>(
        rowp, sorted, H3, AS3, AD3, b3, out);
}

// Round 7
// 256.840 us; speedup vs baseline: 1.0922x; 1.0064x over previous
//
#include <hip/hip_runtime.h>
#include <cmath>

constexpr int NN  = 50000;          // nodes
constexpr int EE  = 800000;         // raw edges
constexpr int E2C = EE + NN;        // edges incl. self loops = 850000

// bucketed counting sort params
constexpr int NBUCK = 256;          // dst buckets
constexpr int BW    = 196;          // bucket width: 196*256 = 50176 >= NN
constexpr int EPT   = 8;            // edges per thread (bin)
constexpr int CH    = 256 * EPT;    // 2048 edges per block
constexpr int NB_B  = (E2C + CH - 1) / CH;  // 416 blocks
constexpr int CAP   = 4096;         // per-bucket pairs capacity
constexpr int SCAP  = 5120;         // per-bucket padded sorted capacity
constexpr int G1ALL = (NN + 63) / 64;       // 782 gemm1 blocks
constexpr int G1A   = 391;                  // gemm1 blocks co-run with bin

using bf16x8 = __attribute__((ext_vector_type(8))) short;
using f32x4  = __attribute__((ext_vector_type(4))) float;

// bf16 helpers (storage bf16, math fp32)
__device__ inline unsigned bf16rne(float f) {
    unsigned u = __builtin_bit_cast(unsigned, f);
    return (u + 0x7fffu + ((u >> 16) & 1u)) >> 16;     // round-nearest-even
}
__device__ inline float bflo(unsigned u) { return __builtin_bit_cast(float, u << 16); }
__device__ inline float bfhi(unsigned u) { return __builtin_bit_cast(float, u & 0xffff0000u); }

// ---------------------------------------------------------------------------
// W[k,c] fp32 -> Wt[c,k] bf16 (all three), + zero bcursor, + write alpha
// sentinels (-1e30 at node NN) and zero h sentinel rows.
// ---------------------------------------------------------------------------
__global__ __launch_bounds__(256) void cvt_weights(
    const float* __restrict__ W1, const float* __restrict__ W2,
    const float* __restrict__ W3,
    unsigned short* __restrict__ W1t, unsigned short* __restrict__ W2t,
    unsigned short* __restrict__ W3t, int* __restrict__ bcursor,
    float* __restrict__ AS1, float* __restrict__ AS2, float* __restrict__ AS3,
    unsigned short* __restrict__ H1, unsigned short* __restrict__ H2,
    unsigned short* __restrict__ H3)
{
    int g = blockIdx.x * 256 + threadIdx.x;
    if (g < NBUCK) bcursor[g] = 0;
    if (g < 4) { AS1[NN * 4 + g] = -1e30f; AS2[NN * 4 + g] = -1e30f; }
    if (g == 4) AS3[NN] = -1e30f;
    if (g < 128) { H1[(size_t)NN * 128 + g] = 0; H2[(size_t)NN * 128 + g] = 0; }
    if (g < 32)  H3[(size_t)NN * 32 + g] = 0;

    const float* W; unsigned short* Wt; int cols;
    if (g < 2048)      { W = W1; Wt = W1t; cols = 128; }
    else if (g < 4096) { W = W2; Wt = W2t; cols = 128; g -= 2048; }
    else if (g < 4608) { W = W3; Wt = W3t; cols = 32;  g -= 4096; }
    else return;
    int c  = g / 16;
    int k8 = (g % 16) * 8;
    unsigned up[4];
    #pragma unroll
    for (int j = 0; j < 4; ++j) {
        float a = W[(k8 + 2 * j) * cols + c];
        float b = W[(k8 + 2 * j + 1) * cols + c];
        up[j] = bf16rne(a) | (bf16rne(b) << 16);
    }
    uint4 u; u.x = up[0]; u.y = up[1]; u.z = up[2]; u.w = up[3];
    *(uint4*)(Wt + c * 128 + k8) = u;
}

// ---------------------------------------------------------------------------
// Layer-1 MFMA GEMM body (64 nodes per bid) + fused alpha dots.
// ---------------------------------------------------------------------------
template<int NT, int NH, bool F32IN>
__device__ inline void gemm_body(
    int bid, const void* __restrict__ inv, const unsigned short* __restrict__ Wt,
    const float* __restrict__ a_s, const float* __restrict__ a_d,
    unsigned short* __restrict__ hout, float* __restrict__ asrc,
    float* __restrict__ adst)
{
    constexpr int COLS = NT * 16;
    constexpr int TPH  = NT / NH;
    const int lane = threadIdx.x & 63;
    const int wave = threadIdx.x >> 6;
    const int m    = lane & 15;
    const int quad = lane >> 4;
    const int n0   = bid * 64 + wave * 16;

    int arow = n0 + m; if (arow >= NN) arow = NN - 1;

    f32x4 acc[NT] = {};
    #pragma unroll
    for (int kq = 0; kq < 4; ++kq) {
        bf16x8 a;
        if constexpr (F32IN) {
            const float* ap = (const float*)inv + (long long)arow * 128 + quad * 8 + kq * 32;
            float4 v0 = *(const float4*)ap;
            float4 v1 = *(const float4*)(ap + 4);
            a[0] = (short)bf16rne(v0.x); a[1] = (short)bf16rne(v0.y);
            a[2] = (short)bf16rne(v0.z); a[3] = (short)bf16rne(v0.w);
            a[4] = (short)bf16rne(v1.x); a[5] = (short)bf16rne(v1.y);
            a[6] = (short)bf16rne(v1.z); a[7] = (short)bf16rne(v1.w);
        } else {
            a = *(const bf16x8*)((const unsigned short*)inv
                    + (long long)arow * 128 + quad * 8 + kq * 32);
        }
        #pragma unroll
        for (int t = 0; t < NT; ++t) {
            bf16x8 b = *(const bf16x8*)(Wt + (t * 16 + m) * 128 + kq * 32 + quad * 8);
            acc[t] = __builtin_amdgcn_mfma_f32_16x16x32_bf16(a, b, acc[t], 0, 0, 0);
        }
    }

    #pragma unroll
    for (int r = 0; r < 4; ++r) {
        int node = n0 + quad * 4 + r;
        if (node < NN) {
            #pragma unroll
            for (int t = 0; t < NT; ++t)
                hout[(long long)node * COLS + t * 16 + m] =
                    (unsigned short)bf16rne(acc[t][r]);
        }
    }

    float asv[NT], adv[NT];
    #pragma unroll
    for (int t = 0; t < NT; ++t) { asv[t] = a_s[t * 16 + m]; adv[t] = a_d[t * 16 + m]; }

    #pragma unroll
    for (int r = 0; r < 4; ++r) {
        const int node = n0 + quad * 4 + r;
        #pragma unroll
        for (int hh = 0; hh < NH; ++hh) {
            float ps = 0.f, pd = 0.f;
            #pragma unroll
            for (int q = 0; q < TPH; ++q) {
                int t = hh * TPH + q;
                ps = fmaf(acc[t][r], asv[t], ps);
                pd = fmaf(acc[t][r], adv[t], pd);
            }
            #pragma unroll
            for (int off = 8; off > 0; off >>= 1) {
                ps += __shfl_down(ps, off, 16);
                pd += __shfl_down(pd, off, 16);
            }
            if (m == 0 && node < NN) {
                asrc[node * NH + hh] = ps;
                adst[node * NH + hh] = pd;
            }
        }
    }
}

// ---------------------------------------------------------------------------
// CSR build bodies. Record: src:16 | dlocal:8 | bucket:8.
// ---------------------------------------------------------------------------
__device__ inline void bin_body(
    int bid, const int* __restrict__ ei, int* __restrict__ bcursor,
    unsigned* __restrict__ pairs)
{
    __shared__ int cnt[NBUCK];
    __shared__ int scanex[NBUCK];
    __shared__ int base[NBUCK];
    __shared__ int cur[NBUCK];
    __shared__ unsigned stage[CH];       // 8 KB

    const int tid = threadIdx.x;
    const long long e0 = (long long)bid * CH;
    cnt[tid] = 0;
    __syncthreads();

    unsigned rec[EPT]; int bk[EPT];
    #pragma unroll
    for (int j = 0; j < EPT; ++j) {
        long long e = e0 + tid + j * 256;
        bool valid = e < E2C;
        int ss = 0, dd = 0;
        if (valid) {
            if (e < EE) { ss = ei[e]; dd = ei[EE + e]; }
            else        { ss = dd = (int)(e - EE); }
        }
        int b = dd / BW;
        bk[j]  = valid ? b : -1;
        rec[j] = (unsigned)ss | ((unsigned)(dd - b * BW) << 16) | ((unsigned)b << 24);
        if (valid) atomicAdd(&cnt[b], 1);
    }
    __syncthreads();

    const int myc = cnt[tid];
    scanex[tid] = myc;
    __syncthreads();
    for (int off = 1; off < NBUCK; off <<= 1) {
        int t = (tid >= off) ? scanex[tid - off] : 0;
        __syncthreads();
        scanex[tid] += t;
        __syncthreads();
    }
    int excl = scanex[tid] - myc;
    __syncthreads();
    scanex[tid] = excl;
    cur[tid]    = excl;
    base[tid]   = atomicAdd(&bcursor[tid], myc);
    __syncthreads();

    #pragma unroll
    for (int j = 0; j < EPT; ++j) {
        if (bk[j] >= 0) {
            int p = atomicAdd(&cur[bk[j]], 1);
            stage[p] = rec[j];
        }
    }
    __syncthreads();

    const int total = (e0 + CH <= E2C) ? CH : (int)(E2C - e0);
    for (int j = tid; j < total; j += 256) {
        unsigned p = stage[j];
        int b = (int)(p >> 24);
        pairs[(size_t)b * CAP + base[b] + (j - scanex[b])] = p;
    }
}

// sort + degree-rank: perm[rank]=node, rowp[rank]=(beg,end), ranks
// degree-sorted within bucket so each 16-rank fused block is uniform.
__device__ inline void sort_body(
    int b, const int* __restrict__ bcursor, const unsigned* __restrict__ pairs,
    int2* __restrict__ rowp, unsigned short* __restrict__ sorted_src,
    unsigned short* __restrict__ perm)
{
    __shared__ int deg[256];
    __shared__ int scn[256];
    __shared__ int cur[256];
    __shared__ int hist2[64];
    __shared__ int scn2[64];
    __shared__ int cur2[64];
    const int n0 = b * BW;
    const int n1 = (n0 + BW < NN) ? n0 + BW : NN;
    const int nloc = n1 - n0;
    const int tid = threadIdx.x;
    const int mycnt = bcursor[b];
    const unsigned* seg = pairs + (size_t)b * CAP;
    const int base = b * SCAP;

    deg[tid] = 0;
    if (tid < 64) hist2[tid] = 0;
    __syncthreads();
    for (int i = tid; i < mycnt; i += 256)
        atomicAdd(&deg[(seg[i] >> 16) & 0xff], 1);
    __syncthreads();

    const int pv = (deg[tid] + 3) & ~3;            // padded degree
    int it = pv >> 2; if (it > 63) it = 63;        // iteration-count key
    scn[tid] = pv;
    if (tid < nloc) atomicAdd(&hist2[it], 1);
    __syncthreads();
    for (int off = 1; off < 256; off <<= 1) {
        int t = (tid >= off) ? scn[tid - off] : 0;
        __syncthreads();
        scn[tid] += t;
        __syncthreads();
    }
    if (tid < 64) scn2[tid] = hist2[tid];
    __syncthreads();
    for (int off = 1; off < 64; off <<= 1) {
        int t = (tid >= off && tid < 64) ? scn2[tid - off] : 0;
        __syncthreads();
        if (tid < 64) scn2[tid] += t;
        __syncthreads();
    }
    if (tid < 64) cur2[tid] = scn2[tid] - hist2[tid];
    __syncthreads();

    const int totalp = scn[255];
    const int pexcl  = scn[tid] - pv;
    cur[tid] = base + pexcl;
    if (tid < nloc) {
        int rank = atomicAdd(&cur2[it], 1);        // degree-sorted local rank
        perm[n0 + rank] = (unsigned short)(n0 + tid);
        rowp[n0 + rank] = make_int2(base + pexcl, base + pexcl + pv);
    }
    __syncthreads();

    int lim = totalp + 8; if (lim > SCAP) lim = SCAP;
    for (int i = tid; i < lim; i += 256)
        sorted_src[base + i] = (unsigned short)NN;
    if (b == NBUCK - 1 && tid < 8)
        sorted_src[NBUCK * SCAP + tid] = (unsigned short)NN;
    __syncthreads();
    for (int i = tid; i < mycnt; i += 256) {
        unsigned p = seg[i];
        int pos = atomicAdd(&cur[(p >> 16) & 0xff], 1);
        sorted_src[pos] = (unsigned short)(p & 0xffff);
    }
}

// ---------------------------------------------------------------------------
// Overlap dispatches: [bin || gemm1 first half], [sort || gemm1 second half]
// ---------------------------------------------------------------------------
__global__ __launch_bounds__(256) void bin_gemm(
    const int* __restrict__ ei, int* __restrict__ bcursor,
    unsigned* __restrict__ pairs,
    const float* __restrict__ x, const unsigned short* __restrict__ Wt,
    const float* __restrict__ a_s, const float* __restrict__ a_d,
    unsigned short* __restrict__ hout, float* __restrict__ asrc,
    float* __restrict__ adst)
{
    if (blockIdx.x < NB_B)
        bin_body(blockIdx.x, ei, bcursor, pairs);
    else
        gemm_body<8, 4, true>(blockIdx.x - NB_B, x, Wt, a_s, a_d, hout, asrc, adst);
}

__global__ __launch_bounds__(256) void sort_gemm(
    const int* __restrict__ bcursor, const unsigned* __restrict__ pairs,
    int2* __restrict__ rowp, unsigned short* __restrict__ sorted_src,
    unsigned short* __restrict__ perm,
    const float* __restrict__ x, const unsigned short* __restrict__ Wt,
    const float* __restrict__ a_s, const float* __restrict__ a_d,
    unsigned short* __restrict__ hout, float* __restrict__ asrc,
    float* __restrict__ adst)
{
    if (blockIdx.x < NBUCK)
        sort_body(blockIdx.x, bcursor, pairs, rowp, sorted_src, perm);
    else
        gemm_body<8, 4, true>(blockIdx.x - NBUCK + G1A, x, Wt, a_s, a_d,
                              hout, asrc, adst);
}

// ---------------------------------------------------------------------------
// Per-node-channel-group CSR aggregation core: padded mask-free 4-deep
// batches, index prefetch one batch ahead; pads -> sentinel node NN.
// d = original node id (for adst); rk = rank (for rowp).
// ---------------------------------------------------------------------------
template<int COLS, int NH, bool DO_ELU>
__device__ inline void aggr_node(
    int d, int rk, int lc,
    const int2* __restrict__ rowp, const unsigned short* __restrict__ sorted_src,
    const unsigned short* __restrict__ hin,
    const float* __restrict__ asrc, const float* __restrict__ adst,
    const float* __restrict__ bias, float v[8])
{
    constexpr int USTR = COLS / 2;            // uints per h row
    const int cc = lc * 8;
    const int head = cc / 32;
    const float ad = adst[d * NH + head];
    const int2 be = rowp[rk];
    const int beg = be.x, end = be.y;         // 4-aligned; deg >= 1
    const uint* hp = (const uint*)hin + cc / 2;

    float num[8] = {};
    float den = 0.f;

    ushort4 sv = *(const ushort4*)&sorted_src[beg];
    for (int i = beg; i < end; i += 4) {
        ushort4 nx = *(const ushort4*)&sorted_src[i + 4];   // slack sentinel-filled
        const int s[4] = {sv.x, sv.y, sv.z, sv.w};
        float a[4];
        uint4 Hv[4];
        #pragma unroll
        for (int j = 0; j < 4; ++j) a[j] = asrc[s[j] * NH + head];
        #pragma unroll
        for (int j = 0; j < 4; ++j)
            Hv[j] = *(const uint4*)&hp[(long long)s[j] * USTR];
        #pragma unroll
        for (int j = 0; j < 4; ++j) {
            float l = a[j] + ad; l = l > 0.f ? l : 0.2f * l;
            float w = __builtin_expf(l);
            den += w;
            num[0] = fmaf(w, bflo(Hv[j].x), num[0]); num[1] = fmaf(w, bfhi(Hv[j].x), num[1]);
            num[2] = fmaf(w, bflo(Hv[j].y), num[2]); num[3] = fmaf(w, bfhi(Hv[j].y), num[3]);
            num[4] = fmaf(w, bflo(Hv[j].z), num[4]); num[5] = fmaf(w, bfhi(Hv[j].z), num[5]);
            num[6] = fmaf(w, bflo(Hv[j].w), num[6]); num[7] = fmaf(w, bfhi(Hv[j].w), num[7]);
        }
        sv = nx;
    }

    float inv = 1.f / (den + 1e-16f);
    #pragma unroll
    for (int j = 0; j < 8; ++j) {
        v[j] = num[j] * inv + bias[cc + j];
        if (DO_ELU) v[j] = v[j] > 0.f ? v[j] : expm1f(v[j]);
    }
}

// ---------------------------------------------------------------------------
// FUSED aggregation + next-layer mini-GEMM. One block owns ranks
// [16*bid, 16*bid+16) — degree-sorted, so the pre-GEMM barrier's
// max-of-16 tail collapses to ~mean. Outputs store at original node ids
// (scattered 256B granules; consumer gathers randomly anyway).
// ---------------------------------------------------------------------------
template<int NT_OUT, int NH_OUT>
__global__ __launch_bounds__(256) void aggr_gemm(
    const unsigned short* __restrict__ perm,
    const int2* __restrict__ rowp, const unsigned short* __restrict__ sorted_src,
    const unsigned short* __restrict__ hin,
    const float* __restrict__ asrc_in, const float* __restrict__ adst_in,
    const float* __restrict__ bias,
    const unsigned short* __restrict__ Wt,
    const float* __restrict__ a_s, const float* __restrict__ a_d,
    unsigned short* __restrict__ hout, float* __restrict__ asrc_out,
    float* __restrict__ adst_out)
{
    __shared__ unsigned short lds_h[16 * 128];   // 4 KB
    __shared__ int lds_node[16];
    const int tid = threadIdx.x;
    const int row = tid / 16;                    // local rank 0..15
    const int lc  = tid % 16;
    const int rk  = blockIdx.x * 16 + row;       // grid exact: rk < NN
    const int d   = perm[rk];
    if (lc == 0) lds_node[row] = d;

    float v[8];
    aggr_node<128, 4, true>(d, rk, lc, rowp, sorted_src, hin, asrc_in, adst_in,
                            bias, v);

    // stage post-ELU output tile to LDS as bf16, swizzled
    uint4 u;
    u.x = bf16rne(v[0]) | (bf16rne(v[1]) << 16);
    u.y = bf16rne(v[2]) | (bf16rne(v[3]) << 16);
    u.z = bf16rne(v[4]) | (bf16rne(v[5]) << 16);
    u.w = bf16rne(v[6]) | (bf16rne(v[7]) << 16);
    *(uint4*)((char*)lds_h + row * 256 + ((lc * 16) ^ ((row & 7) << 4))) = u;
    __syncthreads();

    // ---- mini-GEMM: 16 permuted rows x 128k @ Wt ----
    const int lane = tid & 63;
    const int wave = tid >> 6;
    const int m    = lane & 15;
    const int quad = lane >> 4;
    int t0;
    if constexpr (NT_OUT == 8) t0 = wave * 2;
    else { if (wave != 0) return; t0 = 0; }

    f32x4 acc[2] = {};
    #pragma unroll
    for (int kq = 0; kq < 4; ++kq) {
        int colb = (quad * 16 + kq * 64) ^ ((m & 7) << 4);
        bf16x8 a = *(const bf16x8*)((const char*)lds_h + m * 256 + colb);
        #pragma unroll
        for (int tt = 0; tt < 2; ++tt) {
            bf16x8 b = *(const bf16x8*)(Wt + ((t0 + tt) * 16 + m) * 128
                                        + kq * 32 + quad * 8);
            acc[tt] = __builtin_amdgcn_mfma_f32_16x16x32_bf16(a, b, acc[tt], 0, 0, 0);
        }
    }

    constexpr int COLS_OUT = NT_OUT * 16;
    const int head = t0 / (NT_OUT / NH_OUT);
    float asv[2], adv[2];
    #pragma unroll
    for (int tt = 0; tt < 2; ++tt) {
        asv[tt] = a_s[(t0 + tt) * 16 + m];
        adv[tt] = a_d[(t0 + tt) * 16 + m];
    }

    #pragma unroll
    for (int r = 0; r < 4; ++r) {
        const int node = lds_node[quad * 4 + r];
        #pragma unroll
        for (int tt = 0; tt < 2; ++tt)
            hout[(long long)node * COLS_OUT + (t0 + tt) * 16 + m] =
                (unsigned short)bf16rne(acc[tt][r]);
        float ps = acc[0][r] * asv[0];
        ps = fmaf(acc[1][r], asv[1], ps);
        float pd = acc[0][r] * adv[0];
        pd = fmaf(acc[1][r], adv[1], pd);
        #pragma unroll
        for (int off = 8; off > 0; off >>= 1) {
            ps += __shfl_down(ps, off, 16);
            pd += __shfl_down(pd, off, 16);
        }
        if (m == 0) {
            asrc_out[node * NH_OUT + head] = ps;
            adst_out[node * NH_OUT + head] = pd;
        }
    }
}

// ---------------------------------------------------------------------------
// Final standalone aggregation (layer 3): fp32 output to d_out.
// ---------------------------------------------------------------------------
template<int COLS, int NH>
__global__ __launch_bounds__(256) void aggr_final(
    const unsigned short* __restrict__ perm,
    const int2* __restrict__ rowp, const unsigned short* __restrict__ sorted_src,
    const unsigned short* __restrict__ hin,
    const float* __restrict__ asrc, const float* __restrict__ adst,
    const float* __restrict__ bias, float* __restrict__ out)
{
    constexpr int TPN = COLS / 8;
    int t = blockIdx.x * 256 + threadIdx.x;
    int rk = t / TPN;
    int lc = t % TPN;
    if (rk >= NN) return;
    const int d = perm[rk];
    float v[8];
    aggr_node<COLS, NH, false>(d, rk, lc, rowp, sorted_src, hin, asrc, adst,
                               bias, v);
    float4 o0 = {v[0], v[1], v[2], v[3]};
    float4 o1 = {v[4], v[5], v[6], v[7]};
    *(float4*)&out[(long long)d * COLS + lc * 8]     = o0;
    *(float4*)&out[(long long)d * COLS + lc * 8 + 4] = o1;
}

// ---------------------------------------------------------------------------
extern "C" void kernel_launch(void* const* d_in, const int* in_sizes, int n_in,
                              void* d_out, int out_size, void* d_ws, size_t ws_size,
                              hipStream_t stream)
{
    const float* x   = (const float*)d_in[0];
    const int*   ei  = (const int*)  d_in[1];
    const float* W1  = (const float*)d_in[2];
    const float* as1 = (const float*)d_in[3];
    const float* ad1 = (const float*)d_in[4];
    const float* b1  = (const float*)d_in[5];
    const float* W2  = (const float*)d_in[6];
    const float* as2 = (const float*)d_in[7];
    const float* ad2 = (const float*)d_in[8];
    const float* b2  = (const float*)d_in[9];
    const float* W3  = (const float*)d_in[10];
    const float* as3 = (const float*)d_in[11];
    const float* ad3 = (const float*)d_in[12];
    const float* b3  = (const float*)d_in[13];
    float* out = (float*)d_out;

    // workspace layout (16B-aligned bf16 buffers first); each h has a
    // zeroed sentinel row NN.
    unsigned short* H1  = (unsigned short*)d_ws;          // (N+1)*128 bf16
    unsigned short* H2  = H1 + (size_t)(NN + 1) * 128;    // (N+1)*128 bf16
    unsigned short* H3  = H2 + (size_t)(NN + 1) * 128;    // (N+1)*32 bf16
    unsigned short* W1t = H3 + (size_t)(NN + 1) * 32;     // 128*128 bf16
    unsigned short* W2t = W1t + 128 * 128;
    unsigned short* W3t = W2t + 128 * 128;                // 32*128
    float* AS1 = (float*)(W3t + 32 * 128);                // (N+1)*4
    float* AD1 = AS1 + (size_t)(NN + 1) * 4;              // N*4
    float* AS2 = AD1 + (size_t)NN * 4;                    // (N+1)*4
    float* AD2 = AS2 + (size_t)(NN + 1) * 4;              // N*4
    float* AS3 = AD2 + (size_t)NN * 4;                    // (N+1)
    float* AD3 = AS3 + (size_t)(NN + 1);                  // N
    int2* rowp = (int2*)(AD3 + NN);                       // NN int2 (rank-indexed)
    unsigned short* sorted = (unsigned short*)(rowp + NN);         // NBUCK*SCAP+8
    int* bcursor = (int*)(sorted + (size_t)NBUCK * SCAP + 8);      // NBUCK
    unsigned short* perm = (unsigned short*)(bcursor + NBUCK);     // NN u16
    size_t off = ((size_t)(perm + NN) - (size_t)d_ws + 15) & ~(size_t)15;
    unsigned* pairs = (unsigned*)((char*)d_ws + off);     // NBUCK*CAP u32 (4 MB)

    const int gCvtW  = (4608 + 255) / 256;               // 18
    const int gBinG  = NB_B + G1A;                       // 416 + 391
    const int gSortG = NBUCK + (G1ALL - G1A);            // 256 + 391
    const int gFused = NN / 16;                          // 3125 (exact)
    const int gAggr3 = (NN * 4 + 255) / 256;             // 782

    // 1) weights + sentinels
    cvt_weights<<<gCvtW, 256, 0, stream>>>(W1, W2, W3, W1t, W2t, W3t, bcursor,
                                           AS1, AS2, AS3, H1, H2, H3);
    // 2) edge binning || layer-1 GEMM (first half)
    bin_gemm<<<gBinG, 256, 0, stream>>>(ei, bcursor, pairs,
                                        x, W1t, as1, ad1, H1, AS1, AD1);
    // 3) CSR sort (+degree ranks) || layer-1 GEMM (second half)
    sort_gemm<<<gSortG, 256, 0, stream>>>(bcursor, pairs, rowp, sorted, perm,
                                          x, W1t, as1, ad1, H1, AS1, AD1);
    // 4) aggr layer 1 + GEMM layer 2 (fused, degree-balanced blocks)
    aggr_gemm<8, 4><<<gFused, 256, 0, stream>>>(
        perm, rowp, sorted, H1, AS1, AD1, b1, W2t, as2, ad2, H2, AS2, AD2);
    // 5) aggr layer 2 + GEMM layer 3 (fused)
    aggr_gemm<2, 1><<<gFused, 256, 0, stream>>>(
        perm, rowp, sorted, H2, AS2, AD2, b2, W3t, as3, ad3, H3, AS3, AD3);
    // 6) final aggr layer 3 -> fp32 output
    aggr_final<32, 1><<<gAggr3, 256, 0, stream>>>(
        perm, rowp, sorted, H3, AS3, AD3, b3, out);
}

// Round 8
// 253.570 us; speedup vs baseline: 1.1062x; 1.0129x over previous
//
#include <hip/hip_runtime.h>
#include <cmath>

constexpr int NN  = 50000;          // nodes
constexpr int EE  = 800000;         // raw edges
constexpr int E2C = EE + NN;        // edges incl. self loops = 850000

// bucketed counting sort params
constexpr int NBUCK = 256;          // dst buckets
constexpr int BW    = 196;          // bucket width: 196*256 = 50176 >= NN
constexpr int EPT   = 8;            // edges per thread (bin)
constexpr int CH    = 256 * EPT;    // 2048 edges per block
constexpr int NB_B  = (E2C + CH - 1) / CH;  // 416 blocks
constexpr int CAP   = 4096;         // per-bucket pairs capacity
constexpr int SCAP  = 5120;         // per-bucket padded sorted capacity
constexpr int G1ALL = (NN + 63) / 64;       // 782 gemm1 blocks
constexpr int G1A   = 391;                  // gemm1 blocks co-run with bin

constexpr float RLN2 = 1.44269504088896340736f;   // 1/ln2

using bf16x8 = __attribute__((ext_vector_type(8))) short;
using f32x4  = __attribute__((ext_vector_type(4))) float;

// bf16 helpers (storage bf16, math fp32)
__device__ inline unsigned bf16rne(float f) {
    unsigned u = __builtin_bit_cast(unsigned, f);
    return (u + 0x7fffu + ((u >> 16) & 1u)) >> 16;     // round-nearest-even
}
__device__ inline float bflo(unsigned u) { return __builtin_bit_cast(float, u << 16); }
__device__ inline float bfhi(unsigned u) { return __builtin_bit_cast(float, u & 0xffff0000u); }

// ---------------------------------------------------------------------------
// W[k,c] fp32 -> Wt[c,k] bf16 (all three), + zero bcursor, + write alpha
// sentinels (-1e30 at node NN) and zero h sentinel rows.
// ---------------------------------------------------------------------------
__global__ __launch_bounds__(256) void cvt_weights(
    const float* __restrict__ W1, const float* __restrict__ W2,
    const float* __restrict__ W3,
    unsigned short* __restrict__ W1t, unsigned short* __restrict__ W2t,
    unsigned short* __restrict__ W3t, int* __restrict__ bcursor,
    float* __restrict__ AS1, float* __restrict__ AS2, float* __restrict__ AS3,
    unsigned short* __restrict__ H1, unsigned short* __restrict__ H2,
    unsigned short* __restrict__ H3)
{
    int g = blockIdx.x * 256 + threadIdx.x;
    if (g < NBUCK) bcursor[g] = 0;
    if (g < 4) { AS1[NN * 4 + g] = -1e30f; AS2[NN * 4 + g] = -1e30f; }
    if (g == 4) AS3[NN] = -1e30f;
    if (g < 128) { H1[(size_t)NN * 128 + g] = 0; H2[(size_t)NN * 128 + g] = 0; }
    if (g < 32)  H3[(size_t)NN * 32 + g] = 0;

    const float* W; unsigned short* Wt; int cols;
    if (g < 2048)      { W = W1; Wt = W1t; cols = 128; }
    else if (g < 4096) { W = W2; Wt = W2t; cols = 128; g -= 2048; }
    else if (g < 4608) { W = W3; Wt = W3t; cols = 32;  g -= 4096; }
    else return;
    int c  = g / 16;
    int k8 = (g % 16) * 8;
    unsigned up[4];
    #pragma unroll
    for (int j = 0; j < 4; ++j) {
        float a = W[(k8 + 2 * j) * cols + c];
        float b = W[(k8 + 2 * j + 1) * cols + c];
        up[j] = bf16rne(a) | (bf16rne(b) << 16);
    }
    uint4 u; u.x = up[0]; u.y = up[1]; u.z = up[2]; u.w = up[3];
    *(uint4*)(Wt + c * 128 + k8) = u;
}

// ---------------------------------------------------------------------------
// Layer-1 MFMA GEMM body (64 nodes per bid) + fused alpha dots.
// Alpha dots pre-scaled by 1/ln2 so the aggr inner loop uses native
// v_exp_f32 (2^x) — exp(l) == exp2(l/ln2), and leaky-relu commutes with
// the positive scale.
// ---------------------------------------------------------------------------
template<int NT, int NH, bool F32IN>
__device__ inline void gemm_body(
    int bid, const void* __restrict__ inv, const unsigned short* __restrict__ Wt,
    const float* __restrict__ a_s, const float* __restrict__ a_d,
    unsigned short* __restrict__ hout, float* __restrict__ asrc,
    float* __restrict__ adst)
{
    constexpr int COLS = NT * 16;
    constexpr int TPH  = NT / NH;
    const int lane = threadIdx.x & 63;
    const int wave = threadIdx.x >> 6;
    const int m    = lane & 15;
    const int quad = lane >> 4;
    const int n0   = bid * 64 + wave * 16;

    int arow = n0 + m; if (arow >= NN) arow = NN - 1;

    f32x4 acc[NT] = {};
    #pragma unroll
    for (int kq = 0; kq < 4; ++kq) {
        bf16x8 a;
        if constexpr (F32IN) {
            const float* ap = (const float*)inv + (long long)arow * 128 + quad * 8 + kq * 32;
            float4 v0 = *(const float4*)ap;
            float4 v1 = *(const float4*)(ap + 4);
            a[0] = (short)bf16rne(v0.x); a[1] = (short)bf16rne(v0.y);
            a[2] = (short)bf16rne(v0.z); a[3] = (short)bf16rne(v0.w);
            a[4] = (short)bf16rne(v1.x); a[5] = (short)bf16rne(v1.y);
            a[6] = (short)bf16rne(v1.z); a[7] = (short)bf16rne(v1.w);
        } else {
            a = *(const bf16x8*)((const unsigned short*)inv
                    + (long long)arow * 128 + quad * 8 + kq * 32);
        }
        #pragma unroll
        for (int t = 0; t < NT; ++t) {
            bf16x8 b = *(const bf16x8*)(Wt + (t * 16 + m) * 128 + kq * 32 + quad * 8);
            acc[t] = __builtin_amdgcn_mfma_f32_16x16x32_bf16(a, b, acc[t], 0, 0, 0);
        }
    }

    #pragma unroll
    for (int r = 0; r < 4; ++r) {
        int node = n0 + quad * 4 + r;
        if (node < NN) {
            #pragma unroll
            for (int t = 0; t < NT; ++t)
                hout[(long long)node * COLS + t * 16 + m] =
                    (unsigned short)bf16rne(acc[t][r]);
        }
    }

    float asv[NT], adv[NT];
    #pragma unroll
    for (int t = 0; t < NT; ++t) {
        asv[t] = a_s[t * 16 + m] * RLN2;
        adv[t] = a_d[t * 16 + m] * RLN2;
    }

    #pragma unroll
    for (int r = 0; r < 4; ++r) {
        const int node = n0 + quad * 4 + r;
        #pragma unroll
        for (int hh = 0; hh < NH; ++hh) {
            float ps = 0.f, pd = 0.f;
            #pragma unroll
            for (int q = 0; q < TPH; ++q) {
                int t = hh * TPH + q;
                ps = fmaf(acc[t][r], asv[t], ps);
                pd = fmaf(acc[t][r], adv[t], pd);
            }
            #pragma unroll
            for (int off = 8; off > 0; off >>= 1) {
                ps += __shfl_down(ps, off, 16);
                pd += __shfl_down(pd, off, 16);
            }
            if (m == 0 && node < NN) {
                asrc[node * NH + hh] = ps;
                adst[node * NH + hh] = pd;
            }
        }
    }
}

// ---------------------------------------------------------------------------
// CSR build bodies. Record: src:16 | dlocal:8 | bucket:8.
// ---------------------------------------------------------------------------
__device__ inline void bin_body(
    int bid, const int* __restrict__ ei, int* __restrict__ bcursor,
    unsigned* __restrict__ pairs)
{
    __shared__ int cnt[NBUCK];
    __shared__ int scanex[NBUCK];
    __shared__ int base[NBUCK];
    __shared__ int cur[NBUCK];
    __shared__ unsigned stage[CH];       // 8 KB

    const int tid = threadIdx.x;
    const long long e0 = (long long)bid * CH;
    cnt[tid] = 0;
    __syncthreads();

    unsigned rec[EPT]; int bk[EPT];
    #pragma unroll
    for (int j = 0; j < EPT; ++j) {
        long long e = e0 + tid + j * 256;
        bool valid = e < E2C;
        int ss = 0, dd = 0;
        if (valid) {
            if (e < EE) { ss = ei[e]; dd = ei[EE + e]; }
            else        { ss = dd = (int)(e - EE); }
        }
        int b = dd / BW;
        bk[j]  = valid ? b : -1;
        rec[j] = (unsigned)ss | ((unsigned)(dd - b * BW) << 16) | ((unsigned)b << 24);
        if (valid) atomicAdd(&cnt[b], 1);
    }
    __syncthreads();

    const int myc = cnt[tid];
    scanex[tid] = myc;
    __syncthreads();
    for (int off = 1; off < NBUCK; off <<= 1) {
        int t = (tid >= off) ? scanex[tid - off] : 0;
        __syncthreads();
        scanex[tid] += t;
        __syncthreads();
    }
    int excl = scanex[tid] - myc;
    __syncthreads();
    scanex[tid] = excl;
    cur[tid]    = excl;
    base[tid]   = atomicAdd(&bcursor[tid], myc);
    __syncthreads();

    #pragma unroll
    for (int j = 0; j < EPT; ++j) {
        if (bk[j] >= 0) {
            int p = atomicAdd(&cur[bk[j]], 1);
            stage[p] = rec[j];
        }
    }
    __syncthreads();

    const int total = (e0 + CH <= E2C) ? CH : (int)(E2C - e0);
    for (int j = tid; j < total; j += 256) {
        unsigned p = stage[j];
        int b = (int)(p >> 24);
        pairs[(size_t)b * CAP + base[b] + (j - scanex[b])] = p;
    }
}

// sort + degree-rank: perm[rank]=node, rowp[rank]=(beg,end). Ranks sorted by
// DESCENDING padded degree (LPT: long blocks launch first, short blocks fill
// the drain tail), uniform within each 16-rank fused block.
__device__ inline void sort_body(
    int b, const int* __restrict__ bcursor, const unsigned* __restrict__ pairs,
    int2* __restrict__ rowp, unsigned short* __restrict__ sorted_src,
    unsigned short* __restrict__ perm)
{
    __shared__ int deg[256];
    __shared__ int scn[256];
    __shared__ int cur[256];
    __shared__ int hist2[64];
    __shared__ int scn2[64];
    __shared__ int cur2[64];
    const int n0 = b * BW;
    const int n1 = (n0 + BW < NN) ? n0 + BW : NN;
    const int nloc = n1 - n0;
    const int tid = threadIdx.x;
    const int mycnt = bcursor[b];
    const unsigned* seg = pairs + (size_t)b * CAP;
    const int base = b * SCAP;

    deg[tid] = 0;
    if (tid < 64) hist2[tid] = 0;
    __syncthreads();
    for (int i = tid; i < mycnt; i += 256)
        atomicAdd(&deg[(seg[i] >> 16) & 0xff], 1);
    __syncthreads();

    const int pv = (deg[tid] + 3) & ~3;            // padded degree
    int it = pv >> 2; if (it > 63) it = 63;
    it = 63 - it;                                  // descending-degree key
    scn[tid] = pv;
    if (tid < nloc) atomicAdd(&hist2[it], 1);
    __syncthreads();
    for (int off = 1; off < 256; off <<= 1) {
        int t = (tid >= off) ? scn[tid - off] : 0;
        __syncthreads();
        scn[tid] += t;
        __syncthreads();
    }
    if (tid < 64) scn2[tid] = hist2[tid];
    __syncthreads();
    for (int off = 1; off < 64; off <<= 1) {
        int t = (tid >= off && tid < 64) ? scn2[tid - off] : 0;
        __syncthreads();
        if (tid < 64) scn2[tid] += t;
        __syncthreads();
    }
    if (tid < 64) cur2[tid] = scn2[tid] - hist2[tid];
    __syncthreads();

    const int totalp = scn[255];
    const int pexcl  = scn[tid] - pv;
    cur[tid] = base + pexcl;
    if (tid < nloc) {
        int rank = atomicAdd(&cur2[it], 1);        // degree-sorted local rank
        perm[n0 + rank] = (unsigned short)(n0 + tid);
        rowp[n0 + rank] = make_int2(base + pexcl, base + pexcl + pv);
    }
    __syncthreads();

    int lim = totalp + 8; if (lim > SCAP) lim = SCAP;
    for (int i = tid; i < lim; i += 256)
        sorted_src[base + i] = (unsigned short)NN;
    if (b == NBUCK - 1 && tid < 8)
        sorted_src[NBUCK * SCAP + tid] = (unsigned short)NN;
    __syncthreads();
    for (int i = tid; i < mycnt; i += 256) {
        unsigned p = seg[i];
        int pos = atomicAdd(&cur[(p >> 16) & 0xff], 1);
        sorted_src[pos] = (unsigned short)(p & 0xffff);
    }
}

// ---------------------------------------------------------------------------
// Overlap dispatches: [bin || gemm1 first half], [sort || gemm1 second half]
// ---------------------------------------------------------------------------
__global__ __launch_bounds__(256) void bin_gemm(
    const int* __restrict__ ei, int* __restrict__ bcursor,
    unsigned* __restrict__ pairs,
    const float* __restrict__ x, const unsigned short* __restrict__ Wt,
    const float* __restrict__ a_s, const float* __restrict__ a_d,
    unsigned short* __restrict__ hout, float* __restrict__ asrc,
    float* __restrict__ adst)
{
    if (blockIdx.x < NB_B)
        bin_body(blockIdx.x, ei, bcursor, pairs);
    else
        gemm_body<8, 4, true>(blockIdx.x - NB_B, x, Wt, a_s, a_d, hout, asrc, adst);
}

__global__ __launch_bounds__(256) void sort_gemm(
    const int* __restrict__ bcursor, const unsigned* __restrict__ pairs,
    int2* __restrict__ rowp, unsigned short* __restrict__ sorted_src,
    unsigned short* __restrict__ perm,
    const float* __restrict__ x, const unsigned short* __restrict__ Wt,
    const float* __restrict__ a_s, const float* __restrict__ a_d,
    unsigned short* __restrict__ hout, float* __restrict__ asrc,
    float* __restrict__ adst)
{
    if (blockIdx.x < NBUCK)
        sort_body(blockIdx.x, bcursor, pairs, rowp, sorted_src, perm);
    else
        gemm_body<8, 4, true>(blockIdx.x - NBUCK + G1A, x, Wt, a_s, a_d,
                              hout, asrc, adst);
}

// ---------------------------------------------------------------------------
// Per-node-channel-group CSR aggregation core over [b0, e0): padded
// mask-free 4-deep batches, index prefetch; pads -> sentinel node NN.
// asrc/adst are pre-scaled by 1/ln2: w = v_exp_f32(leaky(a+d)) == exp(orig).
// Accumulates into num[8]/den (caller-owned; may be partial).
// ---------------------------------------------------------------------------
template<int COLS, int NH>
__device__ inline void aggr_range(
    int b0, int e0, int head, float ad,
    const unsigned short* __restrict__ sorted_src,
    const uint* __restrict__ hp,
    const float* __restrict__ asrc,
    float num[8], float& den)
{
    constexpr int USTR = COLS / 2;            // uints per h row
    ushort4 sv = *(const ushort4*)&sorted_src[b0];
    for (int i = b0; i < e0; i += 4) {
        ushort4 nx = *(const ushort4*)&sorted_src[i + 4];   // slack sentinel-filled
        const int s[4] = {sv.x, sv.y, sv.z, sv.w};
        float a[4];
        uint4 Hv[4];
        #pragma unroll
        for (int j = 0; j < 4; ++j) a[j] = asrc[s[j] * NH + head];
        #pragma unroll
        for (int j = 0; j < 4; ++j)
            Hv[j] = *(const uint4*)&hp[(long long)s[j] * USTR];
        #pragma unroll
        for (int j = 0; j < 4; ++j) {
            float l = a[j] + ad; l = l > 0.f ? l : 0.2f * l;
            float w;
            asm("v_exp_f32 %0, %1" : "=v"(w) : "v"(l));     // 2^l
            den += w;
            num[0] = fmaf(w, bflo(Hv[j].x), num[0]); num[1] = fmaf(w, bfhi(Hv[j].x), num[1]);
            num[2] = fmaf(w, bflo(Hv[j].y), num[2]); num[3] = fmaf(w, bfhi(Hv[j].y), num[3]);
            num[4] = fmaf(w, bflo(Hv[j].z), num[4]); num[5] = fmaf(w, bfhi(Hv[j].z), num[5]);
            num[6] = fmaf(w, bflo(Hv[j].w), num[6]); num[7] = fmaf(w, bfhi(Hv[j].w), num[7]);
        }
        sv = nx;
    }
}

// ---------------------------------------------------------------------------
// FUSED aggregation + next-layer mini-GEMM, 512 threads / block:
// 16 ranks x 16 lanes x 2 EDGE-SPLITS. Each split accumulates half of the
// node's edge list (doubles waves/CU and outstanding gathers — aggr is
// gather-latency-bound: r7 VALUBusy 38%, occupancy 50%). Split-1 partials
// combine through LDS, then waves 0-3 run the mini-GEMM as before.
// ---------------------------------------------------------------------------
template<int NT_OUT, int NH_OUT>
__global__ __launch_bounds__(512) void aggr_gemm(
    const unsigned short* __restrict__ perm,
    const int2* __restrict__ rowp, const unsigned short* __restrict__ sorted_src,
    const unsigned short* __restrict__ hin,
    const float* __restrict__ asrc_in, const float* __restrict__ adst_in,
    const float* __restrict__ bias,
    const unsigned short* __restrict__ Wt,
    const float* __restrict__ a_s, const float* __restrict__ a_d,
    unsigned short* __restrict__ hout, float* __restrict__ asrc_out,
    float* __restrict__ adst_out)
{
    __shared__ unsigned short lds_h[16 * 128];   // 4 KB
    __shared__ int lds_node[16];
    __shared__ float lds_p[256][9];              // 9 KB split-1 partials
    const int tid   = threadIdx.x;
    const int split = tid >> 8;
    const int t8    = tid & 255;
    const int row   = t8 >> 4;                   // local rank 0..15
    const int lc    = t8 & 15;
    const int rk    = blockIdx.x * 16 + row;     // grid exact: rk < NN
    const int d     = perm[rk];
    if (split == 0 && lc == 0) lds_node[row] = d;

    const int cc   = lc * 8;
    const int head = cc / 32;
    const float ad = adst_in[d * 4 + head];
    const uint* hp = (const uint*)hin + cc / 2;

    const int2 be = rowp[rk];
    const int beg = be.x, end = be.y;            // 4-aligned
    const int half = (end - beg) >> 1;
    const int mid  = beg + ((half + 3) & ~3);    // beg <= mid <= end, 4-aligned
    const int b0 = split ? mid : beg;
    const int e0 = split ? end : mid;

    float num[8] = {};
    float den = 0.f;
    aggr_range<128, 4>(b0, e0, head, ad, sorted_src, hp, asrc_in, num, den);

    if (split) {
        #pragma unroll
        for (int j = 0; j < 8; ++j) lds_p[t8][j] = num[j];
        lds_p[t8][8] = den;
    }
    __syncthreads();

    if (!split) {
        #pragma unroll
        for (int j = 0; j < 8; ++j) num[j] += lds_p[t8][j];
        den += lds_p[t8][8];
        float inv = 1.f / (den + 1e-16f);
        float v[8];
        #pragma unroll
        for (int j = 0; j < 8; ++j) {
            v[j] = num[j] * inv + bias[cc + j];
            v[j] = v[j] > 0.f ? v[j] : expm1f(v[j]);      // ELU
        }
        // stage post-ELU output tile to LDS as bf16, swizzled
        uint4 u;
        u.x = bf16rne(v[0]) | (bf16rne(v[1]) << 16);
        u.y = bf16rne(v[2]) | (bf16rne(v[3]) << 16);
        u.z = bf16rne(v[4]) | (bf16rne(v[5]) << 16);
        u.w = bf16rne(v[6]) | (bf16rne(v[7]) << 16);
        *(uint4*)((char*)lds_h + row * 256 + ((lc * 16) ^ ((row & 7) << 4))) = u;
    }
    __syncthreads();
    if (split) return;

    // ---- mini-GEMM: 16 permuted rows x 128k @ Wt (waves 0-3) ----
    const int lane = t8 & 63;
    const int wave = t8 >> 6;
    const int m    = lane & 15;
    const int quad = lane >> 4;
    int t0;
    if constexpr (NT_OUT == 8) t0 = wave * 2;
    else { if (wave != 0) return; t0 = 0; }

    f32x4 acc[2] = {};
    #pragma unroll
    for (int kq = 0; kq < 4; ++kq) {
        int colb = (quad * 16 + kq * 64) ^ ((m & 7) << 4);
        bf16x8 a = *(const bf16x8*)((const char*)lds_h + m * 256 + colb);
        #pragma unroll
        for (int tt = 0; tt < 2; ++tt) {
            bf16x8 b = *(const bf16x8*)(Wt + ((t0 + tt) * 16 + m) * 128
                                        + kq * 32 + quad * 8);
            acc[tt] = __builtin_amdgcn_mfma_f32_16x16x32_bf16(a, b, acc[tt], 0, 0, 0);
        }
    }

    constexpr int COLS_OUT = NT_OUT * 16;
    const int headw = t0 / (NT_OUT / NH_OUT);
    float asv[2], adv[2];
    #pragma unroll
    for (int tt = 0; tt < 2; ++tt) {
        asv[tt] = a_s[(t0 + tt) * 16 + m] * RLN2;
        adv[tt] = a_d[(t0 + tt) * 16 + m] * RLN2;
    }

    #pragma unroll
    for (int r = 0; r < 4; ++r) {
        const int node = lds_node[quad * 4 + r];
        #pragma unroll
        for (int tt = 0; tt < 2; ++tt)
            hout[(long long)node * COLS_OUT + (t0 + tt) * 16 + m] =
                (unsigned short)bf16rne(acc[tt][r]);
        float ps = acc[0][r] * asv[0];
        ps = fmaf(acc[1][r], asv[1], ps);
        float pd = acc[0][r] * adv[0];
        pd = fmaf(acc[1][r], adv[1], pd);
        #pragma unroll
        for (int off = 8; off > 0; off >>= 1) {
            ps += __shfl_down(ps, off, 16);
            pd += __shfl_down(pd, off, 16);
        }
        if (m == 0) {
            asrc_out[node * NH_OUT + headw] = ps;
            adst_out[node * NH_OUT + headw] = pd;
        }
    }
}

// ---------------------------------------------------------------------------
// Final standalone aggregation (layer 3): fp32 output to d_out.
// H3 is 3.2 MB (fits per-XCD L2) — gathers mostly L2 hits.
// ---------------------------------------------------------------------------
template<int COLS, int NH>
__global__ __launch_bounds__(256) void aggr_final(
    const unsigned short* __restrict__ perm,
    const int2* __restrict__ rowp, const unsigned short* __restrict__ sorted_src,
    const unsigned short* __restrict__ hin,
    const float* __restrict__ asrc, const float* __restrict__ adst,
    const float* __restrict__ bias, float* __restrict__ out)
{
    constexpr int TPN = COLS / 8;
    int t = blockIdx.x * 256 + threadIdx.x;
    int rk = t / TPN;
    int lc = t % TPN;
    if (rk >= NN) return;
    const int d = perm[rk];
    const int cc = lc * 8;
    const int head = cc / 32;
    const float ad = adst[d * NH + head];
    const int2 be = rowp[rk];
    const uint* hp = (const uint*)hin + cc / 2;
    float num[8] = {};
    float den = 0.f;
    aggr_range<COLS, NH>(be.x, be.y, head, ad, sorted_src, hp, asrc, num, den);
    float inv = 1.f / (den + 1e-16f);
    float v[8];
    #pragma unroll
    for (int j = 0; j < 8; ++j) v[j] = num[j] * inv + bias[cc + j];
    float4 o0 = {v[0], v[1], v[2], v[3]};
    float4 o1 = {v[4], v[5], v[6], v[7]};
    *(float4*)&out[(long long)d * COLS + lc * 8]     = o0;
    *(float4*)&out[(long long)d * COLS + lc * 8 + 4] = o1;
}

// ---------------------------------------------------------------------------
extern "C" void kernel_launch(void* const* d_in, const int* in_sizes, int n_in,
                              void* d_out, int out_size, void* d_ws, size_t ws_size,
                              hipStream_t stream)
{
    const float* x   = (const float*)d_in[0];
    const int*   ei  = (const int*)  d_in[1];
    const float* W1  = (const float*)d_in[2];
    const float* as1 = (const float*)d_in[3];
    const float* ad1 = (const float*)d_in[4];
    const float* b1  = (const float*)d_in[5];
    const float* W2  = (const float*)d_in[6];
    const float* as2 = (const float*)d_in[7];
    const float* ad2 = (const float*)d_in[8];
    const float* b2  = (const float*)d_in[9];
    const float* W3  = (const float*)d_in[10];
    const float* as3 = (const float*)d_in[11];
    const float* ad3 = (const float*)d_in[12];
    const float* b3  = (const float*)d_in[13];
    float* out = (float*)d_out;

    // workspace layout (16B-aligned bf16 buffers first); each h has a
    // zeroed sentinel row NN.
    unsigned short* H1  = (unsigned short*)d_ws;          // (N+1)*128 bf16
    unsigned short* H2  = H1 + (size_t)(NN + 1) * 128;    // (N+1)*128 bf16
    unsigned short* H3  = H2 + (size_t)(NN + 1) * 128;    // (N+1)*32 bf16
    unsigned short* W1t = H3 + (size_t)(NN + 1) * 32;     // 128*128 bf16
    unsigned short* W2t = W1t + 128 * 128;
    unsigned short* W3t = W2t + 128 * 128;                // 32*128
    float* AS1 = (float*)(W3t + 32 * 128);                // (N+1)*4
    float* AD1 = AS1 + (size_t)(NN + 1) * 4;              // N*4
    float* AS2 = AD1 + (size_t)NN * 4;                    // (N+1)*4
    float* AD2 = AS2 + (size_t)(NN + 1) * 4;              // N*4
    float* AS3 = AD2 + (size_t)NN * 4;                    // (N+1)
    float* AD3 = AS3 + (size_t)(NN + 1);                  // N
    int2* rowp = (int2*)(AD3 + NN);                       // NN int2 (rank-indexed)
    unsigned short* sorted = (unsigned short*)(rowp + NN);         // NBUCK*SCAP+8
    int* bcursor = (int*)(sorted + (size_t)NBUCK * SCAP + 8);      // NBUCK
    unsigned short* perm = (unsigned short*)(bcursor + NBUCK);     // NN u16
    size_t off = ((size_t)(perm + NN) - (size_t)d_ws + 15) & ~(size_t)15;
    unsigned* pairs = (unsigned*)((char*)d_ws + off);     // NBUCK*CAP u32 (4 MB)

    const int gCvtW  = (4608 + 255) / 256;               // 18
    const int gBinG  = NB_B + G1A;                       // 416 + 391
    const int gSortG = NBUCK + (G1ALL - G1A);            // 256 + 391
    const int gFused = NN / 16;                          // 3125 (exact)
    const int gAggr3 = (NN * 4 + 255) / 256;             // 782

    // 1) weights + sentinels
    cvt_weights<<<gCvtW, 256, 0, stream>>>(W1, W2, W3, W1t, W2t, W3t, bcursor,
                                           AS1, AS2, AS3, H1, H2, H3);
    // 2) edge binning || layer-1 GEMM (first half)
    bin_gemm<<<gBinG, 256, 0, stream>>>(ei, bcursor, pairs,
                                        x, W1t, as1, ad1, H1, AS1, AD1);
    // 3) CSR sort (+LPT degree ranks) || layer-1 GEMM (second half)
    sort_gemm<<<gSortG, 256, 0, stream>>>(bcursor, pairs, rowp, sorted, perm,
                                          x, W1t, as1, ad1, H1, AS1, AD1);
    // 4) aggr layer 1 + GEMM layer 2 (fused, 2-way edge split, 512 thr)
    aggr_gemm<8, 4><<<gFused, 512, 0, stream>>>(
        perm, rowp, sorted, H1, AS1, AD1, b1, W2t, as2, ad2, H2, AS2, AD2);
    // 5) aggr layer 2 + GEMM layer 3 (fused)
    aggr_gemm<2, 1><<<gFused, 512, 0, stream>>>(
        perm, rowp, sorted, H2, AS2, AD2, b2, W3t, as3, ad3, H3, AS3, AD3);
    // 6) final aggr layer 3 -> fp32 output
    aggr_final<32, 1><<<gAggr3, 256, 0, stream>>>(
        perm, rowp, sorted, H3, AS3, AD3, b3, out);
}